// Round 4
// baseline (530.230 us; speedup 1.0000x reference)
//
#include <hip/hip_runtime.h>

typedef __bf16 bf16;
typedef bf16 bf16x8 __attribute__((ext_vector_type(8)));
typedef float f32x4 __attribute__((ext_vector_type(4)));

#define BB 8
#define TT 8
#define SS 196
#define NTOK 1568           // T*S
#define ROWS 12544          // B*NTOK
#define HH 768
#define HD 64

__device__ __forceinline__ void gload16(const void* g, void* l) {
  __builtin_amdgcn_global_load_lds(
      (const __attribute__((address_space(1))) void*)g,
      (__attribute__((address_space(3))) void*)l, 16, 0, 0);
}

// ---------------- weight transpose f32[K][N] -> bf16[N][K], z-batched -------
__global__ __launch_bounds__(256)
void transpose_w(const float* __restrict__ in, bf16* __restrict__ out, int K, int N) {
  in  += (size_t)blockIdx.z * K * N;
  out += (size_t)blockIdx.z * K * N;
  __shared__ float tile[64][65];
  const int k0 = blockIdx.x * 64, n0 = blockIdx.y * 64;
  const int tx = threadIdx.x & 63, ty = threadIdx.x >> 6;
  #pragma unroll
  for (int rr = ty; rr < 64; rr += 4)
    tile[rr][tx] = in[(size_t)(k0 + rr) * N + n0 + tx];
  __syncthreads();
  #pragma unroll
  for (int rr = ty; rr < 64; rr += 4)
    out[(size_t)(n0 + rr) * K + k0 + tx] = (bf16)tile[tx][rr];
}

// ---------------- layernorm: f32 in -> bf16 out, wave per row ---------------
__global__ __launch_bounds__(256)
void ln_kernel(const float* __restrict__ x, const float* __restrict__ g,
               const float* __restrict__ b, bf16* __restrict__ out) {
  const int row = blockIdx.x * 4 + (threadIdx.x >> 6);
  const int lane = threadIdx.x & 63;
  const float* xr = x + (size_t)row * HH;
  float v[12];
  float sum = 0.f, sq = 0.f;
  #pragma unroll
  for (int i = 0; i < 12; ++i) {
    v[i] = xr[lane + i * 64];
    sum += v[i];
    sq += v[i] * v[i];
  }
  #pragma unroll
  for (int off = 32; off > 0; off >>= 1) {
    sum += __shfl_xor(sum, off);
    sq  += __shfl_xor(sq, off);
  }
  const float mean = sum * (1.f / 768.f);
  const float var = sq * (1.f / 768.f) - mean * mean;
  const float inv = rsqrtf(var + 1e-6f);
  bf16* op = out + (size_t)row * HH;
  #pragma unroll
  for (int i = 0; i < 12; ++i) {
    const int c = lane + i * 64;
    op[c] = (bf16)((v[i] - mean) * inv * g[c] + b[c]);
  }
}

// ---------------- unified GEMM: 128x256 tile, 256 thr (4 waves), 2 blk/CU ---
// C[M,N] = A[M,K](bf16) * BT[N,K](bf16) (+bias)(+resid). 2-buffer LDS,
// counted vmcnt(6) (T3+T4), chunk-XOR swizzle (T2, rule #21), setprio (T5).
// Dense: 1D grid, bijective XCD swizzle (m204), m-fastest per chunk.
// MOE: 2D grid (tile, ncol), row-gather via perm/descs (16 n-idx x 8 batch).
template<bool MOE, bool BIAS, bool RESID, bool OBF16>
__global__ __launch_bounds__(256)
void gemmU(const bf16* __restrict__ A, const bf16* __restrict__ BT,
           const float* __restrict__ bias, const float* __restrict__ resid,
           float* __restrict__ outF, bf16* __restrict__ outB,
           int N, int K, int G,
           const int* __restrict__ perm, const int4* __restrict__ descs,
           const int* __restrict__ meta) {
  __shared__ __align__(16) bf16 lds[2 * 12288];   // per buf: A 4096 + B 8192 elems
  __shared__ int rowLds[128];

  const int tid = threadIdx.x;
  int M0 = 0, N0, ncnt = 16;
  if constexpr (MOE) {
    if ((int)blockIdx.x >= meta[0]) return;
    int4 d = descs[blockIdx.x];
    BT += (size_t)d.x * N * K;
    ncnt = d.z;
    N0 = blockIdx.y * 256;
    if (tid < 128) {
      const int nl = tid >> 3, b = tid & 7;
      const int n = perm[d.y + (nl < ncnt ? nl : ncnt - 1)];
      rowLds[tid] = b * NTOK + n;
    }
    __syncthreads();
  } else {
    const int id = blockIdx.x;
    const int q = G >> 3, r = G & 7, xcd = id & 7, pos = id >> 3;
    const int work = (xcd < r ? xcd * (q + 1) : r * (q + 1) + (xcd - r) * q) + pos;
    M0 = (work % 98) * 128;
    N0 = (work / 98) * 256;
  }

  const int w = tid >> 6, lane = tid & 63;

  // staging map: chunk c -> row c>>2, src seg (c&3)^((c>>3)&3) (rule #21)
  size_t aG[2]; int aL[2];
  #pragma unroll
  for (int i = 0; i < 2; ++i) {
    const int c = tid + i * 256;                 // [0,512)
    const int row = c >> 2, seg = (c & 3) ^ ((c >> 3) & 3);
    const int ar = MOE ? rowLds[row] : (M0 + row);
    aG[i] = (size_t)ar * K + seg * 8;
    aL[i] = c * 8;
  }
  size_t bG[4]; int bL[4];
  #pragma unroll
  for (int i = 0; i < 4; ++i) {
    const int c = tid + i * 256;                 // [0,1024)
    const int row = c >> 2, seg = (c & 3) ^ ((c >> 3) & 3);
    bG[i] = (size_t)(N0 + row) * K + seg * 8;
    bL[i] = 4096 + c * 8;
  }

#define STG(tt) { bf16* bp = lds + ((tt) & 1) * 12288; const int ko = (tt) << 5; \
    gload16(A + aG[0] + ko, bp + aL[0]);                                         \
    gload16(A + aG[1] + ko, bp + aL[1]);                                         \
    gload16(BT + bG[0] + ko, bp + bL[0]);                                        \
    gload16(BT + bG[1] + ko, bp + bL[1]);                                        \
    gload16(BT + bG[2] + ko, bp + bL[2]);                                        \
    gload16(BT + bG[3] + ko, bp + bL[3]); }

  STG(0);
  STG(1);

  f32x4 acc[8][4] = {};
  const int lr = lane & 15, lg = lane >> 4;
  const int xr = ((lr >> 1) & 3) * 8;            // read-side chunk XOR (elems)
  const int NT = K >> 5;

  for (int t = 0; t < NT; ++t) {
    if (t + 1 < NT) { asm volatile("s_waitcnt vmcnt(6)" ::: "memory"); }
    else            { asm volatile("s_waitcnt vmcnt(0)" ::: "memory"); }
    __builtin_amdgcn_s_barrier();
    asm volatile("" ::: "memory");

    const bf16* Ab = lds + (t & 1) * 12288;
    const bf16* Bb = Ab + 4096;
    bf16x8 af[8], bf_[4];
    #pragma unroll
    for (int m = 0; m < 8; ++m)
      af[m] = *(const bf16x8*)&Ab[(m * 16 + lr) * 32 + ((lg * 8) ^ xr)];
    #pragma unroll
    for (int n = 0; n < 4; ++n)
      bf_[n] = *(const bf16x8*)&Bb[(w * 64 + n * 16 + lr) * 32 + ((lg * 8) ^ xr)];

    __builtin_amdgcn_s_setprio(1);
    #pragma unroll
    for (int m = 0; m < 8; ++m)
      #pragma unroll
      for (int n = 0; n < 4; ++n)
        acc[m][n] = __builtin_amdgcn_mfma_f32_16x16x32_bf16(af[m], bf_[n], acc[m][n], 0, 0, 0);
    __builtin_amdgcn_s_setprio(0);

    asm volatile("" ::: "memory");
    __builtin_amdgcn_s_barrier();
    asm volatile("" ::: "memory");
    if (t + 2 < NT) STG(t + 2);
  }
#undef STG

  #pragma unroll
  for (int m = 0; m < 8; ++m) {
    #pragma unroll
    for (int j = 0; j < 4; ++j) {
      const int r = m * 16 + lg * 4 + j;
      if (MOE && ((r >> 3) >= ncnt)) continue;
      const size_t grow = MOE ? (size_t)rowLds[r] : (size_t)(M0 + r);
      const size_t rbase = grow * N;
      #pragma unroll
      for (int n = 0; n < 4; ++n) {
        const int gcol = N0 + w * 64 + n * 16 + lr;
        float v = acc[m][n][j];
        if constexpr (BIAS)  v += bias[gcol];
        if constexpr (RESID) v += resid[rbase + gcol];
        if constexpr (OBF16) outB[rbase + gcol] = (bf16)v;
        else                 outF[rbase + gcol] = v;
      }
    }
  }
}

// ---------------- spatial attention (MFMA): block per (bp, h), 8 waves ------
#define SPAD 208   // keys padded to 13*16
#define VST 232    // Vt / P row stride (2-way bank safe)
__global__ __launch_bounds__(512)
void attn_spatial(const bf16* __restrict__ qkv, bf16* __restrict__ out) {
  __shared__ __align__(16) bf16 Ks[SPAD * 64];
  __shared__ __align__(16) bf16 Vt[64 * VST];
  __shared__ __align__(16) bf16 Pb[8][16 * VST];

  const int bp = blockIdx.x, h = blockIdx.y;
  const int tid = threadIdx.x;
  const int w = tid >> 6, lane = tid & 63;
  const int lr = lane & 15, lg = lane >> 4;
  const size_t base = (size_t)bp * SS * 2304 + h * HD;

  // --- stage K: 208 rows x 8 chunks(16B); src col pre-swizzled by row&7 ----
  for (int cb = w * 64; cb < SPAD * 8; cb += 512) {
    const int c = cb + lane;
    const int row = c >> 3, seg = c & 7;
    const int srow = row < SS ? row : SS - 1;
    const int sseg = seg ^ (row & 7);
    gload16(qkv + base + (size_t)srow * 2304 + 768 + sseg * 8, Ks + cb * 8);
  }
  // --- stage V transposed: task = (key, dseg) -----------------------------
  for (int t = tid; t < 224 * 8; t += 512) {
    const int k = t >> 3, dseg = t & 7;
    const int sk = k < SS ? k : SS - 1;
    bf16x8 v = *(const bf16x8*)(qkv + base + (size_t)sk * 2304 + 1536 + dseg * 8);
    #pragma unroll
    for (int i = 0; i < 8; ++i) Vt[(dseg * 8 + i) * VST + k] = v[i];
  }
  // --- zero P pad cols 208..223 (per wave) --------------------------------
  bf16* Pw = Pb[w];
  for (int i = lane; i < 256; i += 64)
    Pw[(i >> 4) * VST + 208 + (i & 15)] = (bf16)0.f;
  __syncthreads();

  // --- per-wave q-tiles ----------------------------------------------------
  for (int t = w; t < 13; t += 8) {
    const int q0 = t * 16;
    const int qr = q0 + lr;
    const bf16* qp = qkv + base + (size_t)(qr < SS ? qr : SS - 1) * 2304 + lg * 8;
    const bf16x8 af0 = *(const bf16x8*)qp;
    const bf16x8 af1 = *(const bf16x8*)(qp + 32);

    // scores S[16][208]
    f32x4 sc[13];
    #pragma unroll
    for (int f = 0; f < 13; ++f) sc[f] = (f32x4){0.f, 0.f, 0.f, 0.f};
    #pragma unroll
    for (int f = 0; f < 13; ++f) {
      const int key = f * 16 + lr;
      const bf16x8 bv0 = *(const bf16x8*)&Ks[key * 64 + ((lg) ^ (key & 7)) * 8];
      const bf16x8 bv1 = *(const bf16x8*)&Ks[key * 64 + ((4 + lg) ^ (key & 7)) * 8];
      sc[f] = __builtin_amdgcn_mfma_f32_16x16x32_bf16(af0, bv0, sc[f], 0, 0, 0);
      sc[f] = __builtin_amdgcn_mfma_f32_16x16x32_bf16(af1, bv1, sc[f], 0, 0, 0);
    }
    // scale + mask tail cols
    #pragma unroll
    for (int f = 0; f < 13; ++f)
      #pragma unroll
      for (int j = 0; j < 4; ++j) sc[f][j] *= 0.125f;
    if (192 + lr >= SS)
      #pragma unroll
      for (int j = 0; j < 4; ++j) sc[12][j] = -1e30f;

    // softmax over cols (13 frags in-lane + 16-lane group reduce)
    float mx[4], ls[4];
    #pragma unroll
    for (int j = 0; j < 4; ++j) {
      float m = sc[0][j];
      #pragma unroll
      for (int f = 1; f < 13; ++f) m = fmaxf(m, sc[f][j]);
      #pragma unroll
      for (int off = 1; off < 16; off <<= 1) m = fmaxf(m, __shfl_xor(m, off));
      mx[j] = m;
    }
    #pragma unroll
    for (int j = 0; j < 4; ++j) ls[j] = 0.f;
    #pragma unroll
    for (int f = 0; f < 13; ++f) {
      #pragma unroll
      for (int j = 0; j < 4; ++j) {
        const float p = __expf(sc[f][j] - mx[j]);
        ls[j] += p;
        Pw[(lg * 4 + j) * VST + f * 16 + lr] = (bf16)p;
      }
    }
    #pragma unroll
    for (int j = 0; j < 4; ++j) {
      #pragma unroll
      for (int off = 1; off < 16; off <<= 1) ls[j] += __shfl_xor(ls[j], off);
      ls[j] = 1.f / ls[j];
    }

    // PV: O[16][64] = P[16][224] * Vt^T
    f32x4 oacc[4];
    #pragma unroll
    for (int n = 0; n < 4; ++n) oacc[n] = (f32x4){0.f, 0.f, 0.f, 0.f};
    #pragma unroll
    for (int kb = 0; kb < 7; ++kb) {
      const bf16x8 pa = *(const bf16x8*)&Pw[lr * VST + kb * 32 + lg * 8];
      #pragma unroll
      for (int n = 0; n < 4; ++n) {
        const bf16x8 bv = *(const bf16x8*)&Vt[(n * 16 + lr) * VST + kb * 32 + lg * 8];
        oacc[n] = __builtin_amdgcn_mfma_f32_16x16x32_bf16(pa, bv, oacc[n], 0, 0, 0);
      }
    }
    // store
    #pragma unroll
    for (int j = 0; j < 4; ++j) {
      const int row = q0 + lg * 4 + j;
      if (row < SS) {
        bf16* op = out + ((size_t)bp * SS + row) * 768 + h * HD;
        #pragma unroll
        for (int n = 0; n < 4; ++n) op[n * 16 + lr] = (bf16)(oacc[n][j] * ls[j]);
      }
    }
  }
}

// ---------------- temporal attention: wave per (b, s, h), T=8 ---------------
__global__ __launch_bounds__(256)
void attn_temporal(const bf16* __restrict__ qkv, bf16* __restrict__ out) {
  const int pair = blockIdx.x * 4 + (threadIdx.x >> 6);  // (b*196+s)*12 + h
  const int lane = threadIdx.x & 63;
  const int h = pair % 12;
  const int bs = pair / 12;
  const int b = bs / SS, s = bs - b * SS;
  const size_t row0 = (size_t)b * NTOK + s;  // + t*SS
  const int q = lane >> 3, k = lane & 7;
  const bf16* qr = qkv + (row0 + (size_t)q * SS) * 2304 + h * HD;
  const bf16* kr = qkv + (row0 + (size_t)k * SS) * 2304 + 768 + h * HD;
  float sc = 0.f;
  #pragma unroll
  for (int j = 0; j < 8; ++j) {
    bf16x8 qv = ((const bf16x8*)qr)[j];
    bf16x8 kv = ((const bf16x8*)kr)[j];
    #pragma unroll
    for (int d = 0; d < 8; ++d) sc += (float)qv[d] * (float)kv[d];
  }
  sc *= 0.125f;
  float mxv = sc;
  #pragma unroll
  for (int off = 1; off < 8; off <<= 1) mxv = fmaxf(mxv, __shfl_xor(mxv, off));
  float p = __expf(sc - mxv);
  float sum = p;
  #pragma unroll
  for (int off = 1; off < 8; off <<= 1) sum += __shfl_xor(sum, off);
  p /= sum;

  const int dg = lane & 7;
  float o[8] = {0, 0, 0, 0, 0, 0, 0, 0};
  #pragma unroll
  for (int kk = 0; kk < 8; ++kk) {
    const float pk = __shfl(p, (lane & 56) + kk);
    const bf16* vr = qkv + (row0 + (size_t)kk * SS) * 2304 + 1536 + h * HD + dg * 8;
    bf16x8 vv = *(const bf16x8*)vr;
    #pragma unroll
    for (int j = 0; j < 8; ++j) o[j] += pk * (float)vv[j];
  }
  bf16* op = out + (row0 + (size_t)q * SS) * 768 + h * HD + dg * 8;
  bf16x8 ov;
  #pragma unroll
  for (int j = 0; j < 8; ++j) ov[j] = (bf16)o[j];
  *(bf16x8*)op = ov;
}

// ---------------- MoE: bucket n-indices by expert + tile descriptors --------
__global__ __launch_bounds__(256)
void sort_moe(const int* __restrict__ eids, int* __restrict__ perm,
              int4* __restrict__ descs, int* __restrict__ meta) {
  __shared__ int cnt[4], base[4], cur[4];
  const int tid = threadIdx.x;
  if (tid < 4) cnt[tid] = 0;
  __syncthreads();
  for (int n = tid; n < NTOK; n += 256) atomicAdd(&cnt[eids[n]], 1);
  __syncthreads();
  if (tid == 0) {
    int off = 0;
    for (int e = 0; e < 4; ++e) { base[e] = off; cur[e] = off; off += cnt[e]; }
  }
  __syncthreads();
  for (int n = tid; n < NTOK; n += 256) {
    const int pos = atomicAdd(&cur[eids[n]], 1);
    perm[pos] = n;
  }
  if (tid == 0) {
    int t = 0;
    for (int e = 0; e < 4; ++e)
      for (int st = 0; st < cnt[e]; st += 16) {
        const int c = cnt[e] - st;
        descs[t++] = make_int4(e, base[e] + st, c < 16 ? c : 16, 0);
      }
    meta[0] = t;
  }
}

// ---------------- silu(gate)*up ----------------------------------------------
__global__ __launch_bounds__(256)
void silu_mul(const bf16* __restrict__ gu, bf16* __restrict__ out) {
  const size_t i = ((size_t)blockIdx.x * 256 + threadIdx.x) * 4;
  if (i >= (size_t)ROWS * 768) return;
  const size_t row = i / 768, c = i - row * 768;
  const bf16* g = gu + row * 1536 + c;
  const bf16* u = gu + row * 1536 + 768 + c;
  bf16* o = out + i;
  #pragma unroll
  for (int j = 0; j < 4; ++j) {
    const float gv = (float)g[j], uv = (float)u[j];
    const float sv = gv / (1.f + __expf(-gv));
    o[j] = (bf16)(sv * uv);
  }
}

// ---------------- launch ------------------------------------------------------
extern "C" void kernel_launch(void* const* d_in, const int* in_sizes, int n_in,
                              void* d_out, int out_size, void* d_ws, size_t ws_size,
                              hipStream_t stream) {
  (void)in_sizes; (void)n_in; (void)out_size; (void)ws_size;
  const float* x        = (const float*)d_in[0];
  const float* qkv_w_s  = (const float*)d_in[1];
  const float* qkv_b_s  = (const float*)d_in[2];
  const float* proj_w_s = (const float*)d_in[3];
  const float* proj_b_s = (const float*)d_in[4];
  const float* qkv_w_t  = (const float*)d_in[5];
  const float* qkv_b_t  = (const float*)d_in[6];
  const float* proj_w_t = (const float*)d_in[7];
  const float* proj_b_t = (const float*)d_in[8];
  const float* ln_s_g   = (const float*)d_in[9];
  const float* ln_s_b   = (const float*)d_in[10];
  const float* ln_t_g   = (const float*)d_in[11];
  const float* ln_t_b   = (const float*)d_in[12];
  const float* ln_m_g   = (const float*)d_in[13];
  const float* ln_m_b   = (const float*)d_in[14];
  const float* gate_up  = (const float*)d_in[15];
  const float* down_w   = (const float*)d_in[16];
  const int* expert_ids = (const int*)d_in[19];
  float* out = (float*)d_out;

  char* ws = (char*)d_ws;
  bf16* qkvsT   = (bf16*)(ws + 0);
  bf16* projsT  = (bf16*)(ws + 3538944);
  bf16* qkvtT   = (bf16*)(ws + 4718592);
  bf16* projtT  = (bf16*)(ws + 8257536);
  bf16* guT     = (bf16*)(ws + 9437184);
  bf16* downT   = (bf16*)(ws + 18874368);
  bf16* lnbuf   = (bf16*)(ws + 23592960);
  bf16* qkvbuf  = (bf16*)(ws + 42860544);   // also reused as gu (12544x1536)
  bf16* attnbuf = (bf16*)(ws + 100663296);
  float* x1     = (float*)(ws + 119930880);
  int*  perm    = (int*)(ws + 158466048);
  int4* descs   = (int4*)(ws + 158472320);
  int*  meta    = (int*)(ws + 158473952);

  const dim3 blk(256);
  const dim3 blk512(512);

  transpose_w<<<dim3(12, 36, 1), blk, 0, stream>>>(qkv_w_s, qkvsT, 768, 2304);
  transpose_w<<<dim3(12, 12, 1), blk, 0, stream>>>(proj_w_s, projsT, 768, 768);
  transpose_w<<<dim3(12, 36, 1), blk, 0, stream>>>(qkv_w_t, qkvtT, 768, 2304);
  transpose_w<<<dim3(12, 12, 1), blk, 0, stream>>>(proj_w_t, projtT, 768, 768);
  transpose_w<<<dim3(12, 24, 4), blk, 0, stream>>>(gate_up, guT, 768, 1536);
  transpose_w<<<dim3(12, 12, 4), blk, 0, stream>>>(down_w, downT, 768, 768);

  // stage 1: spatial
  ln_kernel<<<3136, blk, 0, stream>>>(x, ln_s_g, ln_s_b, lnbuf);
  gemmU<false, true, false, true><<<dim3(98 * 9), blk, 0, stream>>>(
      lnbuf, qkvsT, qkv_b_s, nullptr, nullptr, qkvbuf, 2304, 768, 98 * 9,
      nullptr, nullptr, nullptr);
  attn_spatial<<<dim3(64, 12), blk512, 0, stream>>>(qkvbuf, attnbuf);
  gemmU<false, true, true, false><<<dim3(98 * 3), blk, 0, stream>>>(
      attnbuf, projsT, proj_b_s, x, x1, nullptr, 768, 768, 98 * 3,
      nullptr, nullptr, nullptr);

  // stage 2: temporal
  ln_kernel<<<3136, blk, 0, stream>>>(x1, ln_t_g, ln_t_b, lnbuf);
  gemmU<false, true, false, true><<<dim3(98 * 9), blk, 0, stream>>>(
      lnbuf, qkvtT, qkv_b_t, nullptr, nullptr, qkvbuf, 2304, 768, 98 * 9,
      nullptr, nullptr, nullptr);
  attn_temporal<<<4704, blk, 0, stream>>>(qkvbuf, attnbuf);
  gemmU<false, true, true, false><<<dim3(98 * 3), blk, 0, stream>>>(
      attnbuf, projtT, proj_b_t, x1, out, nullptr, 768, 768, 98 * 3,
      nullptr, nullptr, nullptr);

  // stage 3: MoE MLP
  ln_kernel<<<3136, blk, 0, stream>>>(out, ln_m_g, ln_m_b, lnbuf);
  sort_moe<<<1, blk, 0, stream>>>(expert_ids, perm, descs, meta);
  gemmU<true, false, false, true><<<dim3(102, 6), blk, 0, stream>>>(
      lnbuf, guT, nullptr, nullptr, nullptr, qkvbuf, 1536, 768, 0,
      perm, descs, meta);
  silu_mul<<<9408, blk, 0, stream>>>(qkvbuf, lnbuf);
  gemmU<true, false, true, false><<<dim3(102, 3), blk, 0, stream>>>(
      lnbuf, downT, nullptr, out, out, nullptr, 768, 768, 0,
      perm, descs, meta);
}

// Round 5
// 428.222 us; speedup vs baseline: 1.2382x; 1.2382x over previous
//
#include <hip/hip_runtime.h>

typedef __bf16 bf16;
typedef bf16 bf16x8 __attribute__((ext_vector_type(8)));
typedef float f32x4 __attribute__((ext_vector_type(4)));

#define BB 8
#define TT 8
#define SS 196
#define NTOK 1568           // T*S
#define ROWS 12544          // B*NTOK
#define HH 768
#define HD 64

__device__ __forceinline__ void gload16(const void* g, void* l) {
  __builtin_amdgcn_global_load_lds(
      (const __attribute__((address_space(1))) void*)g,
      (__attribute__((address_space(3))) void*)l, 16, 0, 0);
}

// ---------------- weight transpose f32[K][N] -> bf16[N][K], z-batched -------
__global__ __launch_bounds__(256)
void transpose_w(const float* __restrict__ in, bf16* __restrict__ out, int K, int N) {
  in  += (size_t)blockIdx.z * K * N;
  out += (size_t)blockIdx.z * K * N;
  __shared__ float tile[64][65];
  const int k0 = blockIdx.x * 64, n0 = blockIdx.y * 64;
  const int tx = threadIdx.x & 63, ty = threadIdx.x >> 6;
  #pragma unroll
  for (int rr = ty; rr < 64; rr += 4)
    tile[rr][tx] = in[(size_t)(k0 + rr) * N + n0 + tx];
  __syncthreads();
  #pragma unroll
  for (int rr = ty; rr < 64; rr += 4)
    out[(size_t)(n0 + rr) * K + k0 + tx] = (bf16)tile[tx][rr];
}

// ---------------- layernorm: f32 in -> bf16 out, wave per row ---------------
__global__ __launch_bounds__(256)
void ln_kernel(const float* __restrict__ x, const float* __restrict__ g,
               const float* __restrict__ b, bf16* __restrict__ out) {
  const int row = blockIdx.x * 4 + (threadIdx.x >> 6);
  const int lane = threadIdx.x & 63;
  const float* xr = x + (size_t)row * HH;
  float v[12];
  float sum = 0.f, sq = 0.f;
  #pragma unroll
  for (int i = 0; i < 12; ++i) {
    v[i] = xr[lane + i * 64];
    sum += v[i];
    sq += v[i] * v[i];
  }
  #pragma unroll
  for (int off = 32; off > 0; off >>= 1) {
    sum += __shfl_xor(sum, off);
    sq  += __shfl_xor(sq, off);
  }
  const float mean = sum * (1.f / 768.f);
  const float var = sq * (1.f / 768.f) - mean * mean;
  const float inv = rsqrtf(var + 1e-6f);
  bf16* op = out + (size_t)row * HH;
  #pragma unroll
  for (int i = 0; i < 12; ++i) {
    const int c = lane + i * 64;
    op[c] = (bf16)((v[i] - mean) * inv * g[c] + b[c]);
  }
}

// ---------------- unified GEMM: 128x128 tile, 256 thr (4 waves), 2 blk/CU ---
// C[M,N] = A[M,K](bf16) * BT[N,K](bf16) (+bias)(+resid). 3-buffer LDS (48KB),
// counted vmcnt(4) (T3/T4 minimum form), chunk-XOR swizzle (T2, rule #21),
// setprio (T5; role diversity comes from 2 co-resident blocks per CU).
// Register budget: acc 64 AGPR + ~110 VGPR < 224 total -> 2 waves/SIMD ->
// TWO independent barrier domains per CU (the R4 goal, without the reg cliff).
// Dense: 1D grid, bijective XCD chunking (m204), n-fastest within chunk so
// each XCD keeps its A-band (~0.7MB) + all B-tiles (<=3.5MB) L2-resident.
// MOE: 2D grid (tile, ncol), row-gather via perm/descs (16 n-idx x 8 batch).
template<bool MOE, bool BIAS, bool RESID, bool OBF16>
__global__ __launch_bounds__(256, 2)
void gemmU(const bf16* __restrict__ A, const bf16* __restrict__ BT,
           const float* __restrict__ bias, const float* __restrict__ resid,
           float* __restrict__ outF, bf16* __restrict__ outB,
           int N, int K, int G, int NTN,
           const int* __restrict__ perm, const int4* __restrict__ descs,
           const int* __restrict__ meta) {
  __shared__ __align__(16) bf16 lds[3 * 8192];   // per buf: A 4096 + B 4096 elems
  __shared__ int rowLds[128];

  const int tid = threadIdx.x;
  int M0 = 0, N0, ncnt = 16;
  if constexpr (MOE) {
    if ((int)blockIdx.x >= meta[0]) return;
    int4 d = descs[blockIdx.x];
    BT += (size_t)d.x * N * K;
    ncnt = d.z;
    N0 = blockIdx.y * 128;
    if (tid < 128) {
      const int nl = tid >> 3, b = tid & 7;
      const int n = perm[d.y + (nl < ncnt ? nl : ncnt - 1)];
      rowLds[tid] = b * NTOK + n;
    }
    __syncthreads();
  } else {
    const int id = blockIdx.x;
    const int q = G >> 3, r = G & 7, xcd = id & 7, pos = id >> 3;
    const int work = (xcd < r ? xcd * (q + 1) : r * (q + 1) + (xcd - r) * q) + pos;
    const int mt = work / NTN, nt = work - mt * NTN;   // n-fastest in chunk
    M0 = mt * 128;
    N0 = nt * 128;
  }

  const int w = tid >> 6, lane = tid & 63;
  const int wr = w >> 1, wc = w & 1;

  // staging map: chunk c in [0,512) -> row c>>2, src seg (c&3)^((c>>3)&3)
  size_t aG[2], bG[2]; int aL[2], bL[2];
  #pragma unroll
  for (int i = 0; i < 2; ++i) {
    const int c = tid + i * 256;
    const int row = c >> 2, seg = (c & 3) ^ ((c >> 3) & 3);
    const int ar = MOE ? rowLds[row] : (M0 + row);
    aG[i] = (size_t)ar * K + seg * 8;
    aL[i] = c * 8;
    bG[i] = (size_t)(N0 + row) * K + seg * 8;
    bL[i] = 4096 + c * 8;
  }

#define STG(tt) { bf16* bp = lds + ((tt) % 3) * 8192; const int ko = (tt) << 5; \
    gload16(A + aG[0] + ko, bp + aL[0]);                                        \
    gload16(A + aG[1] + ko, bp + aL[1]);                                        \
    gload16(BT + bG[0] + ko, bp + bL[0]);                                       \
    gload16(BT + bG[1] + ko, bp + bL[1]); }

  STG(0);
  STG(1);

  f32x4 acc[4][4] = {};
  const int lr = lane & 15, lg = lane >> 4;
  const int xr = ((lr >> 1) & 3) * 8;            // read-side chunk XOR (elems)
  const int NT = K >> 5;

  for (int t = 0; t < NT; ++t) {
    if (t + 1 < NT) { asm volatile("s_waitcnt vmcnt(4)" ::: "memory"); }
    else            { asm volatile("s_waitcnt vmcnt(0)" ::: "memory"); }
    __builtin_amdgcn_s_barrier();
    asm volatile("" ::: "memory");

    const bf16* Ab = lds + (t % 3) * 8192;
    const bf16* Bb = Ab + 4096;
    bf16x8 af[4], bf_[4];
    #pragma unroll
    for (int m = 0; m < 4; ++m)
      af[m] = *(const bf16x8*)&Ab[(wr * 64 + m * 16 + lr) * 32 + ((lg * 8) ^ xr)];
    #pragma unroll
    for (int n = 0; n < 4; ++n)
      bf_[n] = *(const bf16x8*)&Bb[(wc * 64 + n * 16 + lr) * 32 + ((lg * 8) ^ xr)];

    __builtin_amdgcn_s_setprio(1);
    #pragma unroll
    for (int m = 0; m < 4; ++m)
      #pragma unroll
      for (int n = 0; n < 4; ++n)
        acc[m][n] = __builtin_amdgcn_mfma_f32_16x16x32_bf16(af[m], bf_[n], acc[m][n], 0, 0, 0);
    __builtin_amdgcn_s_setprio(0);

    asm volatile("" ::: "memory");
    __builtin_amdgcn_s_barrier();
    asm volatile("" ::: "memory");
    if (t + 2 < NT) STG(t + 2);
  }
#undef STG

  #pragma unroll
  for (int m = 0; m < 4; ++m) {
    #pragma unroll
    for (int j = 0; j < 4; ++j) {
      const int r = wr * 64 + m * 16 + lg * 4 + j;
      if (MOE && ((r >> 3) >= ncnt)) continue;
      const size_t grow = MOE ? (size_t)rowLds[r] : (size_t)(M0 + r);
      const size_t rbase = grow * N;
      #pragma unroll
      for (int n = 0; n < 4; ++n) {
        const int gcol = N0 + wc * 64 + n * 16 + lr;
        float v = acc[m][n][j];
        if constexpr (BIAS)  v += bias[gcol];
        if constexpr (RESID) v += resid[rbase + gcol];
        if constexpr (OBF16) outB[rbase + gcol] = (bf16)v;
        else                 outF[rbase + gcol] = v;
      }
    }
  }
}

// ---------------- spatial attention (MFMA): block per (bp, h), 8 waves ------
#define SPAD 208   // keys padded to 13*16
#define VST 232    // Vt / P row stride (2-way bank safe)
__global__ __launch_bounds__(512)
void attn_spatial(const bf16* __restrict__ qkv, bf16* __restrict__ out) {
  __shared__ __align__(16) bf16 Ks[SPAD * 64];
  __shared__ __align__(16) bf16 Vt[64 * VST];
  __shared__ __align__(16) bf16 Pb[8][16 * VST];

  const int bp = blockIdx.x, h = blockIdx.y;
  const int tid = threadIdx.x;
  const int w = tid >> 6, lane = tid & 63;
  const int lr = lane & 15, lg = lane >> 4;
  const size_t base = (size_t)bp * SS * 2304 + h * HD;

  // --- stage K: 208 rows x 8 chunks(16B); src col pre-swizzled by row&7 ----
  for (int cb = w * 64; cb < SPAD * 8; cb += 512) {
    const int c = cb + lane;
    const int row = c >> 3, seg = c & 7;
    const int srow = row < SS ? row : SS - 1;
    const int sseg = seg ^ (row & 7);
    gload16(qkv + base + (size_t)srow * 2304 + 768 + sseg * 8, Ks + cb * 8);
  }
  // --- stage V transposed: task = (key, dseg) -----------------------------
  for (int t = tid; t < 224 * 8; t += 512) {
    const int k = t >> 3, dseg = t & 7;
    const int sk = k < SS ? k : SS - 1;
    bf16x8 v = *(const bf16x8*)(qkv + base + (size_t)sk * 2304 + 1536 + dseg * 8);
    #pragma unroll
    for (int i = 0; i < 8; ++i) Vt[(dseg * 8 + i) * VST + k] = v[i];
  }
  // --- zero P pad cols 208..223 (per wave) --------------------------------
  bf16* Pw = Pb[w];
  for (int i = lane; i < 256; i += 64)
    Pw[(i >> 4) * VST + 208 + (i & 15)] = (bf16)0.f;
  __syncthreads();

  // --- per-wave q-tiles ----------------------------------------------------
  for (int t = w; t < 13; t += 8) {
    const int q0 = t * 16;
    const int qr = q0 + lr;
    const bf16* qp = qkv + base + (size_t)(qr < SS ? qr : SS - 1) * 2304 + lg * 8;
    const bf16x8 af0 = *(const bf16x8*)qp;
    const bf16x8 af1 = *(const bf16x8*)(qp + 32);

    // scores S[16][208]
    f32x4 sc[13];
    #pragma unroll
    for (int f = 0; f < 13; ++f) sc[f] = (f32x4){0.f, 0.f, 0.f, 0.f};
    #pragma unroll
    for (int f = 0; f < 13; ++f) {
      const int key = f * 16 + lr;
      const bf16x8 bv0 = *(const bf16x8*)&Ks[key * 64 + ((lg) ^ (key & 7)) * 8];
      const bf16x8 bv1 = *(const bf16x8*)&Ks[key * 64 + ((4 + lg) ^ (key & 7)) * 8];
      sc[f] = __builtin_amdgcn_mfma_f32_16x16x32_bf16(af0, bv0, sc[f], 0, 0, 0);
      sc[f] = __builtin_amdgcn_mfma_f32_16x16x32_bf16(af1, bv1, sc[f], 0, 0, 0);
    }
    // scale + mask tail cols
    #pragma unroll
    for (int f = 0; f < 13; ++f)
      #pragma unroll
      for (int j = 0; j < 4; ++j) sc[f][j] *= 0.125f;
    if (192 + lr >= SS)
      #pragma unroll
      for (int j = 0; j < 4; ++j) sc[12][j] = -1e30f;

    // softmax over cols (13 frags in-lane + 16-lane group reduce)
    float mx[4], ls[4];
    #pragma unroll
    for (int j = 0; j < 4; ++j) {
      float m = sc[0][j];
      #pragma unroll
      for (int f = 1; f < 13; ++f) m = fmaxf(m, sc[f][j]);
      #pragma unroll
      for (int off = 1; off < 16; off <<= 1) m = fmaxf(m, __shfl_xor(m, off));
      mx[j] = m;
    }
    #pragma unroll
    for (int j = 0; j < 4; ++j) ls[j] = 0.f;
    #pragma unroll
    for (int f = 0; f < 13; ++f) {
      #pragma unroll
      for (int j = 0; j < 4; ++j) {
        const float p = __expf(sc[f][j] - mx[j]);
        ls[j] += p;
        Pw[(lg * 4 + j) * VST + f * 16 + lr] = (bf16)p;
      }
    }
    #pragma unroll
    for (int j = 0; j < 4; ++j) {
      #pragma unroll
      for (int off = 1; off < 16; off <<= 1) ls[j] += __shfl_xor(ls[j], off);
      ls[j] = 1.f / ls[j];
    }

    // PV: O[16][64] = P[16][224] * Vt^T
    f32x4 oacc[4];
    #pragma unroll
    for (int n = 0; n < 4; ++n) oacc[n] = (f32x4){0.f, 0.f, 0.f, 0.f};
    #pragma unroll
    for (int kb = 0; kb < 7; ++kb) {
      const bf16x8 pa = *(const bf16x8*)&Pw[lr * VST + kb * 32 + lg * 8];
      #pragma unroll
      for (int n = 0; n < 4; ++n) {
        const bf16x8 bv = *(const bf16x8*)&Vt[(n * 16 + lr) * VST + kb * 32 + lg * 8];
        oacc[n] = __builtin_amdgcn_mfma_f32_16x16x32_bf16(pa, bv, oacc[n], 0, 0, 0);
      }
    }
    // store
    #pragma unroll
    for (int j = 0; j < 4; ++j) {
      const int row = q0 + lg * 4 + j;
      if (row < SS) {
        bf16* op = out + ((size_t)bp * SS + row) * 768 + h * HD;
        #pragma unroll
        for (int n = 0; n < 4; ++n) op[n * 16 + lr] = (bf16)(oacc[n][j] * ls[j]);
      }
    }
  }
}

// ---------------- temporal attention: wave per (b, s, h), T=8 ---------------
__global__ __launch_bounds__(256)
void attn_temporal(const bf16* __restrict__ qkv, bf16* __restrict__ out) {
  const int pair = blockIdx.x * 4 + (threadIdx.x >> 6);  // (b*196+s)*12 + h
  const int lane = threadIdx.x & 63;
  const int h = pair % 12;
  const int bs = pair / 12;
  const int b = bs / SS, s = bs - b * SS;
  const size_t row0 = (size_t)b * NTOK + s;  // + t*SS
  const int q = lane >> 3, k = lane & 7;
  const bf16* qr = qkv + (row0 + (size_t)q * SS) * 2304 + h * HD;
  const bf16* kr = qkv + (row0 + (size_t)k * SS) * 2304 + 768 + h * HD;
  float sc = 0.f;
  #pragma unroll
  for (int j = 0; j < 8; ++j) {
    bf16x8 qv = ((const bf16x8*)qr)[j];
    bf16x8 kv = ((const bf16x8*)kr)[j];
    #pragma unroll
    for (int d = 0; d < 8; ++d) sc += (float)qv[d] * (float)kv[d];
  }
  sc *= 0.125f;
  float mxv = sc;
  #pragma unroll
  for (int off = 1; off < 8; off <<= 1) mxv = fmaxf(mxv, __shfl_xor(mxv, off));
  float p = __expf(sc - mxv);
  float sum = p;
  #pragma unroll
  for (int off = 1; off < 8; off <<= 1) sum += __shfl_xor(sum, off);
  p /= sum;

  const int dg = lane & 7;
  float o[8] = {0, 0, 0, 0, 0, 0, 0, 0};
  #pragma unroll
  for (int kk = 0; kk < 8; ++kk) {
    const float pk = __shfl(p, (lane & 56) + kk);
    const bf16* vr = qkv + (row0 + (size_t)kk * SS) * 2304 + 1536 + h * HD + dg * 8;
    bf16x8 vv = *(const bf16x8*)vr;
    #pragma unroll
    for (int j = 0; j < 8; ++j) o[j] += pk * (float)vv[j];
  }
  bf16* op = out + (row0 + (size_t)q * SS) * 768 + h * HD + dg * 8;
  bf16x8 ov;
  #pragma unroll
  for (int j = 0; j < 8; ++j) ov[j] = (bf16)o[j];
  *(bf16x8*)op = ov;
}

// ---------------- MoE: bucket n-indices by expert + tile descriptors --------
__global__ __launch_bounds__(256)
void sort_moe(const int* __restrict__ eids, int* __restrict__ perm,
              int4* __restrict__ descs, int* __restrict__ meta) {
  __shared__ int cnt[4], base[4], cur[4];
  const int tid = threadIdx.x;
  if (tid < 4) cnt[tid] = 0;
  __syncthreads();
  for (int n = tid; n < NTOK; n += 256) atomicAdd(&cnt[eids[n]], 1);
  __syncthreads();
  if (tid == 0) {
    int off = 0;
    for (int e = 0; e < 4; ++e) { base[e] = off; cur[e] = off; off += cnt[e]; }
  }
  __syncthreads();
  for (int n = tid; n < NTOK; n += 256) {
    const int pos = atomicAdd(&cur[eids[n]], 1);
    perm[pos] = n;
  }
  if (tid == 0) {
    int t = 0;
    for (int e = 0; e < 4; ++e)
      for (int st = 0; st < cnt[e]; st += 16) {
        const int c = cnt[e] - st;
        descs[t++] = make_int4(e, base[e] + st, c < 16 ? c : 16, 0);
      }
    meta[0] = t;
  }
}

// ---------------- silu(gate)*up ----------------------------------------------
__global__ __launch_bounds__(256)
void silu_mul(const bf16* __restrict__ gu, bf16* __restrict__ out) {
  const size_t i = ((size_t)blockIdx.x * 256 + threadIdx.x) * 4;
  if (i >= (size_t)ROWS * 768) return;
  const size_t row = i / 768, c = i - row * 768;
  const bf16* g = gu + row * 1536 + c;
  const bf16* u = gu + row * 1536 + 768 + c;
  bf16* o = out + i;
  #pragma unroll
  for (int j = 0; j < 4; ++j) {
    const float gv = (float)g[j], uv = (float)u[j];
    const float sv = gv / (1.f + __expf(-gv));
    o[j] = (bf16)(sv * uv);
  }
}

// ---------------- launch ------------------------------------------------------
extern "C" void kernel_launch(void* const* d_in, const int* in_sizes, int n_in,
                              void* d_out, int out_size, void* d_ws, size_t ws_size,
                              hipStream_t stream) {
  (void)in_sizes; (void)n_in; (void)out_size; (void)ws_size;
  const float* x        = (const float*)d_in[0];
  const float* qkv_w_s  = (const float*)d_in[1];
  const float* qkv_b_s  = (const float*)d_in[2];
  const float* proj_w_s = (const float*)d_in[3];
  const float* proj_b_s = (const float*)d_in[4];
  const float* qkv_w_t  = (const float*)d_in[5];
  const float* qkv_b_t  = (const float*)d_in[6];
  const float* proj_w_t = (const float*)d_in[7];
  const float* proj_b_t = (const float*)d_in[8];
  const float* ln_s_g   = (const float*)d_in[9];
  const float* ln_s_b   = (const float*)d_in[10];
  const float* ln_t_g   = (const float*)d_in[11];
  const float* ln_t_b   = (const float*)d_in[12];
  const float* ln_m_g   = (const float*)d_in[13];
  const float* ln_m_b   = (const float*)d_in[14];
  const float* gate_up  = (const float*)d_in[15];
  const float* down_w   = (const float*)d_in[16];
  const int* expert_ids = (const int*)d_in[19];
  float* out = (float*)d_out;

  char* ws = (char*)d_ws;
  bf16* qkvsT   = (bf16*)(ws + 0);
  bf16* projsT  = (bf16*)(ws + 3538944);
  bf16* qkvtT   = (bf16*)(ws + 4718592);
  bf16* projtT  = (bf16*)(ws + 8257536);
  bf16* guT     = (bf16*)(ws + 9437184);
  bf16* downT   = (bf16*)(ws + 18874368);
  bf16* lnbuf   = (bf16*)(ws + 23592960);
  bf16* qkvbuf  = (bf16*)(ws + 42860544);   // also reused as gu (12544x1536)
  bf16* attnbuf = (bf16*)(ws + 100663296);
  float* x1     = (float*)(ws + 119930880);
  int*  perm    = (int*)(ws + 158466048);
  int4* descs   = (int4*)(ws + 158472320);
  int*  meta    = (int*)(ws + 158473952);

  const dim3 blk(256);
  const dim3 blk512(512);

  transpose_w<<<dim3(12, 36, 1), blk, 0, stream>>>(qkv_w_s, qkvsT, 768, 2304);
  transpose_w<<<dim3(12, 12, 1), blk, 0, stream>>>(proj_w_s, projsT, 768, 768);
  transpose_w<<<dim3(12, 36, 1), blk, 0, stream>>>(qkv_w_t, qkvtT, 768, 2304);
  transpose_w<<<dim3(12, 12, 1), blk, 0, stream>>>(proj_w_t, projtT, 768, 768);
  transpose_w<<<dim3(12, 24, 4), blk, 0, stream>>>(gate_up, guT, 768, 1536);
  transpose_w<<<dim3(12, 12, 4), blk, 0, stream>>>(down_w, downT, 768, 768);

  // stage 1: spatial
  ln_kernel<<<3136, blk, 0, stream>>>(x, ln_s_g, ln_s_b, lnbuf);
  gemmU<false, true, false, true><<<dim3(98 * 18), blk, 0, stream>>>(
      lnbuf, qkvsT, qkv_b_s, nullptr, nullptr, qkvbuf, 2304, 768, 98 * 18, 18,
      nullptr, nullptr, nullptr);
  attn_spatial<<<dim3(64, 12), blk512, 0, stream>>>(qkvbuf, attnbuf);
  gemmU<false, true, true, false><<<dim3(98 * 6), blk, 0, stream>>>(
      attnbuf, projsT, proj_b_s, x, x1, nullptr, 768, 768, 98 * 6, 6,
      nullptr, nullptr, nullptr);

  // stage 2: temporal
  ln_kernel<<<3136, blk, 0, stream>>>(x1, ln_t_g, ln_t_b, lnbuf);
  gemmU<false, true, false, true><<<dim3(98 * 18), blk, 0, stream>>>(
      lnbuf, qkvtT, qkv_b_t, nullptr, nullptr, qkvbuf, 2304, 768, 98 * 18, 18,
      nullptr, nullptr, nullptr);
  attn_temporal<<<4704, blk, 0, stream>>>(qkvbuf, attnbuf);
  gemmU<false, true, true, false><<<dim3(98 * 6), blk, 0, stream>>>(
      attnbuf, projtT, proj_b_t, x1, out, nullptr, 768, 768, 98 * 6, 6,
      nullptr, nullptr, nullptr);

  // stage 3: MoE MLP
  ln_kernel<<<3136, blk, 0, stream>>>(out, ln_m_g, ln_m_b, lnbuf);
  sort_moe<<<1, blk, 0, stream>>>(expert_ids, perm, descs, meta);
  gemmU<true, false, false, true><<<dim3(102, 12), blk, 0, stream>>>(
      lnbuf, guT, nullptr, nullptr, nullptr, qkvbuf, 1536, 768, 0, 0,
      perm, descs, meta);
  silu_mul<<<9408, blk, 0, stream>>>(qkvbuf, lnbuf);
  gemmU<true, false, true, false><<<dim3(102, 6), blk, 0, stream>>>(
      lnbuf, downT, nullptr, out, out, nullptr, 768, 768, 0, 0,
      perm, descs, meta);
}

// Round 6
// 410.904 us; speedup vs baseline: 1.2904x; 1.0421x over previous
//
#include <hip/hip_runtime.h>

typedef __bf16 bf16;
typedef bf16 bf16x8 __attribute__((ext_vector_type(8)));
typedef float f32x4 __attribute__((ext_vector_type(4)));

#define BB 8
#define TT 8
#define SS 196
#define NTOK 1568           // T*S
#define ROWS 12544          // B*NTOK
#define HH 768
#define HD 64

__device__ __forceinline__ void gload16(const void* g, void* l) {
  __builtin_amdgcn_global_load_lds(
      (const __attribute__((address_space(1))) void*)g,
      (__attribute__((address_space(3))) void*)l, 16, 0, 0);
}

#define BAR() do { asm volatile("" ::: "memory"); __builtin_amdgcn_s_barrier(); \
                   asm volatile("" ::: "memory"); } while (0)
#define VM2() asm volatile("s_waitcnt vmcnt(2)" ::: "memory")
#define VM0() asm volatile("s_waitcnt vmcnt(0)" ::: "memory")

// ---------------- weight transpose f32[K][N] -> bf16[N][K], z-batched -------
__global__ __launch_bounds__(256)
void transpose_w(const float* __restrict__ in, bf16* __restrict__ out, int K, int N) {
  in  += (size_t)blockIdx.z * K * N;
  out += (size_t)blockIdx.z * K * N;
  __shared__ float tile[64][65];
  const int k0 = blockIdx.x * 64, n0 = blockIdx.y * 64;
  const int tx = threadIdx.x & 63, ty = threadIdx.x >> 6;
  #pragma unroll
  for (int rr = ty; rr < 64; rr += 4)
    tile[rr][tx] = in[(size_t)(k0 + rr) * N + n0 + tx];
  __syncthreads();
  #pragma unroll
  for (int rr = ty; rr < 64; rr += 4)
    out[(size_t)(n0 + rr) * K + k0 + tx] = (bf16)tile[tx][rr];
}

// ---------------- layernorm: f32 in -> bf16 out, wave per row ---------------
__global__ __launch_bounds__(256)
void ln_kernel(const float* __restrict__ x, const float* __restrict__ g,
               const float* __restrict__ b, bf16* __restrict__ out) {
  const int row = blockIdx.x * 4 + (threadIdx.x >> 6);
  const int lane = threadIdx.x & 63;
  const float* xr = x + (size_t)row * HH;
  float v[12];
  float sum = 0.f, sq = 0.f;
  #pragma unroll
  for (int i = 0; i < 12; ++i) {
    v[i] = xr[lane + i * 64];
    sum += v[i];
    sq += v[i] * v[i];
  }
  #pragma unroll
  for (int off = 32; off > 0; off >>= 1) {
    sum += __shfl_xor(sum, off);
    sq  += __shfl_xor(sq, off);
  }
  const float mean = sum * (1.f / 768.f);
  const float var = sq * (1.f / 768.f) - mean * mean;
  const float inv = rsqrtf(var + 1e-6f);
  bf16* op = out + (size_t)row * HH;
  #pragma unroll
  for (int i = 0; i < 12; ++i) {
    const int c = lane + i * 64;
    op[c] = (bf16)((v[i] - mean) * inv * g[c] + b[c]);
  }
}

// ---------------- 8-phase 256x256 GEMM (T3+T4+T2+T5), BK=64, 2 K-tiles/iter -
// C[M,N] = A[M,K](bf16) * BT[N,K](bf16). 512 thr = 8 waves (2M x 4N), wave
// tile 128x64, acc[8][4]. LDS 128KB = 2 dbuf x (A 256x64 + B 256x64).
// dbuf[kt&1]. Per iter i (kt 2i,2i+1): 8 phases, each stages ONE half-tile
// (128 rows, 2 gload16/thread) + ds-reads one quadrant + 16 MFMA + barrier.
// Stage schedule (hazard-audited: each stage issues >=1 barrier after the
// last read of the region it overwrites):
//   p1:A1(2i+1) p2:B0(2i+1) p3:B1(2i+1) p4:A0(2i+2)
//   p5:A1(2i+2) p6:B0(2i+2) p7:B1(2i+2) p8:A0(2i+3)
// vmcnt(2) at p4 (guards kt 2i+1 complete) and p8 (guards 2i+2) — never 0
// in steady state (1 half-tile stays in flight). Chunk-XOR swizzle
// seg^(row&7), both-sides (rule #21): 2 lanes/16B chunk = conflict-free.
// MOE: desc = 32 tokens x 8 batch = 256 gathered rows.
template<bool MOE, bool BIAS, bool RESID, bool OBF16>
__global__ __launch_bounds__(512, 2)
void gemm8p(const bf16* __restrict__ A, const bf16* __restrict__ BT,
            const float* __restrict__ bias, const float* __restrict__ resid,
            float* __restrict__ outF, bf16* __restrict__ outB,
            int N, int K, int NMT,
            const int* __restrict__ perm, const int4* __restrict__ descs,
            const int* __restrict__ meta) {
  __shared__ __align__(16) bf16 lds[2 * 32768];   // 128 KB
  __shared__ int rowLds[256];

  const int tid = threadIdx.x;
  int M0 = 0, N0, ncnt = 32;
  if constexpr (MOE) {
    if ((int)blockIdx.x >= meta[0]) return;
    int4 d = descs[blockIdx.x];
    BT += (size_t)d.x * N * K;
    ncnt = d.z;
    N0 = blockIdx.y * 256;
    if (tid < 256) {
      const int nl = tid >> 3, b = tid & 7;
      const int n = perm[d.y + (nl < ncnt ? nl : ncnt - 1)];
      rowLds[tid] = b * NTOK + n;
    }
    __syncthreads();
  } else {
    const int G = gridDim.x;
    const int q = G >> 3, r = G & 7, xcd = blockIdx.x & 7, pos = blockIdx.x >> 3;
    const int work = (xcd < r ? xcd * (q + 1) : r * (q + 1) + (xcd - r) * q) + pos;
    const int mt = work % NMT, nt = work / NMT;    // m-fastest in chunk
    M0 = mt * 256;
    N0 = nt * 256;
  }

  const int w = tid >> 6, lane = tid & 63;
  const int wr = w >> 2, wc = w & 3;
  const int lr = lane & 15, lg = lane >> 4;

  // staging constants: thread handles chunks tid and tid+512 of each 128-row
  // half-tile; chunk c -> row c>>3 (0..127), LDS seg c&7, src seg ^(row&7).
  const int srow0 = tid >> 3;            // 0..63
  const int srow1 = 64 + srow0;
  const int sseg0 = (tid & 7) ^ (srow0 & 7);
  const int sseg1 = (tid & 7) ^ (srow1 & 7);
  int ar00, ar01, ar10, ar11;
  if constexpr (MOE) {
    ar00 = rowLds[srow0];        ar01 = rowLds[srow1];
    ar10 = rowLds[128 + srow0];  ar11 = rowLds[128 + srow1];
  } else {
    ar00 = M0 + srow0;           ar01 = M0 + srow1;
    ar10 = M0 + 128 + srow0;     ar11 = M0 + 128 + srow1;
  }
  const bf16* aP00 = A + (size_t)ar00 * K + sseg0 * 8;
  const bf16* aP01 = A + (size_t)ar01 * K + sseg1 * 8;
  const bf16* aP10 = A + (size_t)ar10 * K + sseg0 * 8;
  const bf16* aP11 = A + (size_t)ar11 * K + sseg1 * 8;
  const bf16* bP00 = BT + (size_t)(N0 + srow0) * K + sseg0 * 8;
  const bf16* bP01 = BT + (size_t)(N0 + srow1) * K + sseg1 * 8;
  const bf16* bP10 = BT + (size_t)(N0 + 128 + srow0) * K + sseg0 * 8;
  const bf16* bP11 = BT + (size_t)(N0 + 128 + srow1) * K + sseg1 * 8;

  auto STG = [&](const bf16* P0, const bf16* P1, int dstoff, int kt) {
    bf16* d_ = lds + dstoff;
    gload16(P0 + (size_t)kt * 64, d_ + tid * 8);
    gload16(P1 + (size_t)kt * 64, d_ + 4096 + tid * 8);
  };
  auto LDA = [&](int dd, int mh, bf16x8* D) {
    #pragma unroll
    for (int mf = 0; mf < 4; ++mf) {
      const int ra = wr * 128 + mh * 64 + mf * 16 + lr;
      const bf16* p = lds + dd * 32768 + ra * 64;
      D[mf * 2 + 0] = *(const bf16x8*)(p + ((lg ^ (lr & 7)) * 8));
      D[mf * 2 + 1] = *(const bf16x8*)(p + (((4 + lg) ^ (lr & 7)) * 8));
    }
  };
  auto LDB = [&](int dd, int nh, bf16x8* D) {
    #pragma unroll
    for (int nf = 0; nf < 2; ++nf) {
      const int rb = wc * 64 + nh * 32 + nf * 16 + lr;
      const bf16* p = lds + dd * 32768 + 16384 + rb * 64;
      D[nf * 2 + 0] = *(const bf16x8*)(p + ((lg ^ (lr & 7)) * 8));
      D[nf * 2 + 1] = *(const bf16x8*)(p + (((4 + lg) ^ (lr & 7)) * 8));
    }
  };

  f32x4 acc[8][4] = {};
  auto MM = [&](const bf16x8* AF, const bf16x8* BF, int mh, int nh) {
    __builtin_amdgcn_s_setprio(1);
    #pragma unroll
    for (int mf = 0; mf < 4; ++mf)
      #pragma unroll
      for (int nf = 0; nf < 2; ++nf) {
        f32x4 c = acc[mh * 4 + mf][nh * 2 + nf];
        c = __builtin_amdgcn_mfma_f32_16x16x32_bf16(AF[mf * 2 + 0], BF[nf * 2 + 0], c, 0, 0, 0);
        c = __builtin_amdgcn_mfma_f32_16x16x32_bf16(AF[mf * 2 + 1], BF[nf * 2 + 1], c, 0, 0, 0);
        acc[mh * 4 + mf][nh * 2 + nf] = c;
      }
    __builtin_amdgcn_s_setprio(0);
  };

  const int NI = K >> 7;   // iterations (128 K each); K % 128 == 0

  // prologue: kt0 all 4 halves + kt1 A0; wait kt0 (vmcnt(2): A0(1) in flight)
  STG(aP00, aP01, 0, 0);
  STG(aP10, aP11, 8192, 0);
  STG(bP00, bP01, 16384, 0);
  STG(bP10, bP11, 24576, 0);
  STG(aP00, aP01, 32768, 1);
  VM2();
  BAR();

  bf16x8 a[8], b[4], b2[4];
  for (int i = 0; i < NI; ++i) {
    const bool last = (i == NI - 1);
    const int k1 = 2 * i + 1, k2 = 2 * i + 2, k3 = 2 * i + 3;
    // p1: kt0 Q(0,0) | stage A1(odd)->dbuf1
    STG(aP10, aP11, 32768 + 8192, k1);
    LDA(0, 0, a); LDB(0, 0, b);
    MM(a, b, 0, 0);
    BAR();
    // p2: Q(0,1) | stage B0(odd)
    STG(bP00, bP01, 32768 + 16384, k1);
    LDB(0, 1, b2);
    MM(a, b2, 0, 1);
    BAR();
    // p3: Q(1,1) | stage B1(odd)
    STG(bP10, bP11, 32768 + 24576, k1);
    LDA(0, 1, a);
    MM(a, b2, 1, 1);
    BAR();
    // p4: Q(1,0) | stage A0(2i+2)->dbuf0 ; vmcnt guards kt 2i+1 complete
    if (!last) STG(aP00, aP01, 0, k2);
    LDB(0, 0, b);
    MM(a, b, 1, 0);
    if (!last) { VM2(); } else { VM0(); }
    BAR();
    // p5: kt1 Q(0,0) | stage A1(2i+2)
    if (!last) STG(aP10, aP11, 8192, k2);
    LDA(1, 0, a); LDB(1, 0, b);
    MM(a, b, 0, 0);
    BAR();
    // p6: Q(0,1) | stage B0(2i+2)
    if (!last) STG(bP00, bP01, 16384, k2);
    LDB(1, 1, b2);
    MM(a, b2, 0, 1);
    BAR();
    // p7: Q(1,1) | stage B1(2i+2)
    if (!last) STG(bP10, bP11, 24576, k2);
    LDA(1, 1, a);
    MM(a, b2, 1, 1);
    BAR();
    // p8: Q(1,0) | stage A0(2i+3)->dbuf1 ; vmcnt guards kt 2i+2 complete
    if (!last) STG(aP00, aP01, 32768, k3);
    LDB(1, 0, b);
    MM(a, b, 1, 0);
    if (!last) { VM2(); BAR(); }
  }

  #pragma unroll
  for (int m = 0; m < 8; ++m) {
    #pragma unroll
    for (int j = 0; j < 4; ++j) {
      const int r = wr * 128 + m * 16 + lg * 4 + j;
      if (MOE && ((r >> 3) >= ncnt)) continue;
      const size_t grow = MOE ? (size_t)rowLds[r] : (size_t)(M0 + r);
      const size_t rbase = grow * N;
      #pragma unroll
      for (int n = 0; n < 4; ++n) {
        const int gcol = N0 + wc * 64 + n * 16 + lr;
        float v = acc[m][n][j];
        if constexpr (BIAS)  v += bias[gcol];
        if constexpr (RESID) v += resid[rbase + gcol];
        if constexpr (OBF16) outB[rbase + gcol] = (bf16)v;
        else                 outF[rbase + gcol] = v;
      }
    }
  }
}

// ---------------- 2-phase 128x128 GEMM (proj: N=768 underfills 256 tiles) ---
template<bool MOE, bool BIAS, bool RESID, bool OBF16>
__global__ __launch_bounds__(256, 2)
void gemmU(const bf16* __restrict__ A, const bf16* __restrict__ BT,
           const float* __restrict__ bias, const float* __restrict__ resid,
           float* __restrict__ outF, bf16* __restrict__ outB,
           int N, int K, int G, int NTN,
           const int* __restrict__ perm, const int4* __restrict__ descs,
           const int* __restrict__ meta) {
  __shared__ __align__(16) bf16 lds[3 * 8192];

  const int tid = threadIdx.x;
  int M0, N0;
  {
    const int id = blockIdx.x;
    const int q = G >> 3, r = G & 7, xcd = id & 7, pos = id >> 3;
    const int work = (xcd < r ? xcd * (q + 1) : r * (q + 1) + (xcd - r) * q) + pos;
    const int mt = work / NTN, nt = work - mt * NTN;
    M0 = mt * 128;
    N0 = nt * 128;
  }

  const int w = tid >> 6, lane = tid & 63;
  const int wr = w >> 1, wc = w & 1;

  size_t aG[2], bG[2]; int aL[2], bL[2];
  #pragma unroll
  for (int i = 0; i < 2; ++i) {
    const int c = tid + i * 256;
    const int row = c >> 2, seg = (c & 3) ^ ((c >> 3) & 3);
    aG[i] = (size_t)(M0 + row) * K + seg * 8;
    aL[i] = c * 8;
    bG[i] = (size_t)(N0 + row) * K + seg * 8;
    bL[i] = 4096 + c * 8;
  }

#define STGU(tt) { bf16* bp = lds + ((tt) % 3) * 8192; const int ko = (tt) << 5; \
    gload16(A + aG[0] + ko, bp + aL[0]);                                        \
    gload16(A + aG[1] + ko, bp + aL[1]);                                        \
    gload16(BT + bG[0] + ko, bp + bL[0]);                                       \
    gload16(BT + bG[1] + ko, bp + bL[1]); }

  STGU(0);
  STGU(1);

  f32x4 acc[4][4] = {};
  const int lr = lane & 15, lg = lane >> 4;
  const int xr = ((lr >> 1) & 3) * 8;
  const int NT = K >> 5;

  for (int t = 0; t < NT; ++t) {
    if (t + 1 < NT) { asm volatile("s_waitcnt vmcnt(4)" ::: "memory"); }
    else            { asm volatile("s_waitcnt vmcnt(0)" ::: "memory"); }
    __builtin_amdgcn_s_barrier();
    asm volatile("" ::: "memory");

    const bf16* Ab = lds + (t % 3) * 8192;
    const bf16* Bb = Ab + 4096;
    bf16x8 af[4], bf_[4];
    #pragma unroll
    for (int m = 0; m < 4; ++m)
      af[m] = *(const bf16x8*)&Ab[(wr * 64 + m * 16 + lr) * 32 + ((lg * 8) ^ xr)];
    #pragma unroll
    for (int n = 0; n < 4; ++n)
      bf_[n] = *(const bf16x8*)&Bb[(wc * 64 + n * 16 + lr) * 32 + ((lg * 8) ^ xr)];

    __builtin_amdgcn_s_setprio(1);
    #pragma unroll
    for (int m = 0; m < 4; ++m)
      #pragma unroll
      for (int n = 0; n < 4; ++n)
        acc[m][n] = __builtin_amdgcn_mfma_f32_16x16x32_bf16(af[m], bf_[n], acc[m][n], 0, 0, 0);
    __builtin_amdgcn_s_setprio(0);

    asm volatile("" ::: "memory");
    __builtin_amdgcn_s_barrier();
    asm volatile("" ::: "memory");
    if (t + 2 < NT) STGU(t + 2);
  }
#undef STGU

  #pragma unroll
  for (int m = 0; m < 4; ++m) {
    #pragma unroll
    for (int j = 0; j < 4; ++j) {
      const int r = wr * 64 + m * 16 + lg * 4 + j;
      const size_t rbase = (size_t)(M0 + r) * N;
      #pragma unroll
      for (int n = 0; n < 4; ++n) {
        const int gcol = N0 + wc * 64 + n * 16 + lr;
        float v = acc[m][n][j];
        if constexpr (BIAS)  v += bias[gcol];
        if constexpr (RESID) v += resid[rbase + gcol];
        if constexpr (OBF16) outB[rbase + gcol] = (bf16)v;
        else                 outF[rbase + gcol] = v;
      }
    }
  }
}

// ---------------- spatial attention (MFMA): block per (bp, h), 8 waves ------
#define SPAD 208   // keys padded to 13*16
#define VST 232    // Vt / P row stride (2-way bank safe)
__global__ __launch_bounds__(512)
void attn_spatial(const bf16* __restrict__ qkv, bf16* __restrict__ out) {
  __shared__ __align__(16) bf16 Ks[SPAD * 64];
  __shared__ __align__(16) bf16 Vt[64 * VST];
  __shared__ __align__(16) bf16 Pb[8][16 * VST];

  const int bp = blockIdx.x, h = blockIdx.y;
  const int tid = threadIdx.x;
  const int w = tid >> 6, lane = tid & 63;
  const int lr = lane & 15, lg = lane >> 4;
  const size_t base = (size_t)bp * SS * 2304 + h * HD;

  for (int cb = w * 64; cb < SPAD * 8; cb += 512) {
    const int c = cb + lane;
    const int row = c >> 3, seg = c & 7;
    const int srow = row < SS ? row : SS - 1;
    const int sseg = seg ^ (row & 7);
    gload16(qkv + base + (size_t)srow * 2304 + 768 + sseg * 8, Ks + cb * 8);
  }
  for (int t = tid; t < 224 * 8; t += 512) {
    const int k = t >> 3, dseg = t & 7;
    const int sk = k < SS ? k : SS - 1;
    bf16x8 v = *(const bf16x8*)(qkv + base + (size_t)sk * 2304 + 1536 + dseg * 8);
    #pragma unroll
    for (int i = 0; i < 8; ++i) Vt[(dseg * 8 + i) * VST + k] = v[i];
  }
  bf16* Pw = Pb[w];
  for (int i = lane; i < 256; i += 64)
    Pw[(i >> 4) * VST + 208 + (i & 15)] = (bf16)0.f;
  __syncthreads();

  for (int t = w; t < 13; t += 8) {
    const int q0 = t * 16;
    const int qr = q0 + lr;
    const bf16* qp = qkv + base + (size_t)(qr < SS ? qr : SS - 1) * 2304 + lg * 8;
    const bf16x8 af0 = *(const bf16x8*)qp;
    const bf16x8 af1 = *(const bf16x8*)(qp + 32);

    f32x4 sc[13];
    #pragma unroll
    for (int f = 0; f < 13; ++f) sc[f] = (f32x4){0.f, 0.f, 0.f, 0.f};
    #pragma unroll
    for (int f = 0; f < 13; ++f) {
      const int key = f * 16 + lr;
      const bf16x8 bv0 = *(const bf16x8*)&Ks[key * 64 + ((lg) ^ (key & 7)) * 8];
      const bf16x8 bv1 = *(const bf16x8*)&Ks[key * 64 + ((4 + lg) ^ (key & 7)) * 8];
      sc[f] = __builtin_amdgcn_mfma_f32_16x16x32_bf16(af0, bv0, sc[f], 0, 0, 0);
      sc[f] = __builtin_amdgcn_mfma_f32_16x16x32_bf16(af1, bv1, sc[f], 0, 0, 0);
    }
    #pragma unroll
    for (int f = 0; f < 13; ++f)
      #pragma unroll
      for (int j = 0; j < 4; ++j) sc[f][j] *= 0.125f;
    if (192 + lr >= SS)
      #pragma unroll
      for (int j = 0; j < 4; ++j) sc[12][j] = -1e30f;

    float mx[4], ls[4];
    #pragma unroll
    for (int j = 0; j < 4; ++j) {
      float m = sc[0][j];
      #pragma unroll
      for (int f = 1; f < 13; ++f) m = fmaxf(m, sc[f][j]);
      #pragma unroll
      for (int off = 1; off < 16; off <<= 1) m = fmaxf(m, __shfl_xor(m, off));
      mx[j] = m;
    }
    #pragma unroll
    for (int j = 0; j < 4; ++j) ls[j] = 0.f;
    #pragma unroll
    for (int f = 0; f < 13; ++f) {
      #pragma unroll
      for (int j = 0; j < 4; ++j) {
        const float p = __expf(sc[f][j] - mx[j]);
        ls[j] += p;
        Pw[(lg * 4 + j) * VST + f * 16 + lr] = (bf16)p;
      }
    }
    #pragma unroll
    for (int j = 0; j < 4; ++j) {
      #pragma unroll
      for (int off = 1; off < 16; off <<= 1) ls[j] += __shfl_xor(ls[j], off);
      ls[j] = 1.f / ls[j];
    }

    f32x4 oacc[4];
    #pragma unroll
    for (int n = 0; n < 4; ++n) oacc[n] = (f32x4){0.f, 0.f, 0.f, 0.f};
    #pragma unroll
    for (int kb = 0; kb < 7; ++kb) {
      const bf16x8 pa = *(const bf16x8*)&Pw[lr * VST + kb * 32 + lg * 8];
      #pragma unroll
      for (int n = 0; n < 4; ++n) {
        const bf16x8 bv = *(const bf16x8*)&Vt[(n * 16 + lr) * VST + kb * 32 + lg * 8];
        oacc[n] = __builtin_amdgcn_mfma_f32_16x16x32_bf16(pa, bv, oacc[n], 0, 0, 0);
      }
    }
    #pragma unroll
    for (int j = 0; j < 4; ++j) {
      const int row = q0 + lg * 4 + j;
      if (row < SS) {
        bf16* op = out + ((size_t)bp * SS + row) * 768 + h * HD;
        #pragma unroll
        for (int n = 0; n < 4; ++n) op[n * 16 + lr] = (bf16)(oacc[n][j] * ls[j]);
      }
    }
  }
}

// ---------------- temporal attention: wave per (b, s, h), T=8 ---------------
__global__ __launch_bounds__(256)
void attn_temporal(const bf16* __restrict__ qkv, bf16* __restrict__ out) {
  const int pair = blockIdx.x * 4 + (threadIdx.x >> 6);
  const int lane = threadIdx.x & 63;
  const int h = pair % 12;
  const int bs = pair / 12;
  const int b = bs / SS, s = bs - b * SS;
  const size_t row0 = (size_t)b * NTOK + s;
  const int q = lane >> 3, k = lane & 7;
  const bf16* qr = qkv + (row0 + (size_t)q * SS) * 2304 + h * HD;
  const bf16* kr = qkv + (row0 + (size_t)k * SS) * 2304 + 768 + h * HD;
  float sc = 0.f;
  #pragma unroll
  for (int j = 0; j < 8; ++j) {
    bf16x8 qv = ((const bf16x8*)qr)[j];
    bf16x8 kv = ((const bf16x8*)kr)[j];
    #pragma unroll
    for (int d = 0; d < 8; ++d) sc += (float)qv[d] * (float)kv[d];
  }
  sc *= 0.125f;
  float mxv = sc;
  #pragma unroll
  for (int off = 1; off < 8; off <<= 1) mxv = fmaxf(mxv, __shfl_xor(mxv, off));
  float p = __expf(sc - mxv);
  float sum = p;
  #pragma unroll
  for (int off = 1; off < 8; off <<= 1) sum += __shfl_xor(sum, off);
  p /= sum;

  const int dg = lane & 7;
  float o[8] = {0, 0, 0, 0, 0, 0, 0, 0};
  #pragma unroll
  for (int kk = 0; kk < 8; ++kk) {
    const float pk = __shfl(p, (lane & 56) + kk);
    const bf16* vr = qkv + (row0 + (size_t)kk * SS) * 2304 + 1536 + h * HD + dg * 8;
    bf16x8 vv = *(const bf16x8*)vr;
    #pragma unroll
    for (int j = 0; j < 8; ++j) o[j] += pk * (float)vv[j];
  }
  bf16* op = out + (row0 + (size_t)q * SS) * 768 + h * HD + dg * 8;
  bf16x8 ov;
  #pragma unroll
  for (int j = 0; j < 8; ++j) ov[j] = (bf16)o[j];
  *(bf16x8*)op = ov;
}

// ---------------- MoE: bucket n-indices by expert + 32-token descriptors ----
__global__ __launch_bounds__(256)
void sort_moe(const int* __restrict__ eids, int* __restrict__ perm,
              int4* __restrict__ descs, int* __restrict__ meta) {
  __shared__ int cnt[4], base[4], cur[4];
  const int tid = threadIdx.x;
  if (tid < 4) cnt[tid] = 0;
  __syncthreads();
  for (int n = tid; n < NTOK; n += 256) atomicAdd(&cnt[eids[n]], 1);
  __syncthreads();
  if (tid == 0) {
    int off = 0;
    for (int e = 0; e < 4; ++e) { base[e] = off; cur[e] = off; off += cnt[e]; }
  }
  __syncthreads();
  for (int n = tid; n < NTOK; n += 256) {
    const int pos = atomicAdd(&cur[eids[n]], 1);
    perm[pos] = n;
  }
  if (tid == 0) {
    int t = 0;
    for (int e = 0; e < 4; ++e)
      for (int st = 0; st < cnt[e]; st += 32) {
        const int c = cnt[e] - st;
        descs[t++] = make_int4(e, base[e] + st, c < 32 ? c : 32, 0);
      }
    meta[0] = t;
  }
}

// ---------------- silu(gate)*up ----------------------------------------------
__global__ __launch_bounds__(256)
void silu_mul(const bf16* __restrict__ gu, bf16* __restrict__ out) {
  const size_t i = ((size_t)blockIdx.x * 256 + threadIdx.x) * 4;
  if (i >= (size_t)ROWS * 768) return;
  const size_t row = i / 768, c = i - row * 768;
  const bf16* g = gu + row * 1536 + c;
  const bf16* u = gu + row * 1536 + 768 + c;
  bf16* o = out + i;
  #pragma unroll
  for (int j = 0; j < 4; ++j) {
    const float gv = (float)g[j], uv = (float)u[j];
    const float sv = gv / (1.f + __expf(-gv));
    o[j] = (bf16)(sv * uv);
  }
}

// ---------------- launch ------------------------------------------------------
extern "C" void kernel_launch(void* const* d_in, const int* in_sizes, int n_in,
                              void* d_out, int out_size, void* d_ws, size_t ws_size,
                              hipStream_t stream) {
  (void)in_sizes; (void)n_in; (void)out_size; (void)ws_size;
  const float* x        = (const float*)d_in[0];
  const float* qkv_w_s  = (const float*)d_in[1];
  const float* qkv_b_s  = (const float*)d_in[2];
  const float* proj_w_s = (const float*)d_in[3];
  const float* proj_b_s = (const float*)d_in[4];
  const float* qkv_w_t  = (const float*)d_in[5];
  const float* qkv_b_t  = (const float*)d_in[6];
  const float* proj_w_t = (const float*)d_in[7];
  const float* proj_b_t = (const float*)d_in[8];
  const float* ln_s_g   = (const float*)d_in[9];
  const float* ln_s_b   = (const float*)d_in[10];
  const float* ln_t_g   = (const float*)d_in[11];
  const float* ln_t_b   = (const float*)d_in[12];
  const float* ln_m_g   = (const float*)d_in[13];
  const float* ln_m_b   = (const float*)d_in[14];
  const float* gate_up  = (const float*)d_in[15];
  const float* down_w   = (const float*)d_in[16];
  const int* expert_ids = (const int*)d_in[19];
  float* out = (float*)d_out;

  char* ws = (char*)d_ws;
  bf16* qkvsT   = (bf16*)(ws + 0);
  bf16* projsT  = (bf16*)(ws + 3538944);
  bf16* qkvtT   = (bf16*)(ws + 4718592);
  bf16* projtT  = (bf16*)(ws + 8257536);
  bf16* guT     = (bf16*)(ws + 9437184);
  bf16* downT   = (bf16*)(ws + 18874368);
  bf16* lnbuf   = (bf16*)(ws + 23592960);
  bf16* qkvbuf  = (bf16*)(ws + 42860544);   // also reused as gu (12544x1536)
  bf16* attnbuf = (bf16*)(ws + 100663296);
  float* x1     = (float*)(ws + 119930880);
  int*  perm    = (int*)(ws + 158466048);
  int4* descs   = (int4*)(ws + 158472320);
  int*  meta    = (int*)(ws + 158473952);

  const dim3 blk(256);
  const dim3 blk512(512);

  transpose_w<<<dim3(12, 36, 1), blk, 0, stream>>>(qkv_w_s, qkvsT, 768, 2304);
  transpose_w<<<dim3(12, 12, 1), blk, 0, stream>>>(proj_w_s, projsT, 768, 768);
  transpose_w<<<dim3(12, 36, 1), blk, 0, stream>>>(qkv_w_t, qkvtT, 768, 2304);
  transpose_w<<<dim3(12, 12, 1), blk, 0, stream>>>(proj_w_t, projtT, 768, 768);
  transpose_w<<<dim3(12, 24, 4), blk, 0, stream>>>(gate_up, guT, 768, 1536);
  transpose_w<<<dim3(12, 12, 4), blk, 0, stream>>>(down_w, downT, 768, 768);

  // stage 1: spatial
  ln_kernel<<<3136, blk, 0, stream>>>(x, ln_s_g, ln_s_b, lnbuf);
  gemm8p<false, true, false, true><<<dim3(49 * 9), blk512, 0, stream>>>(
      lnbuf, qkvsT, qkv_b_s, nullptr, nullptr, qkvbuf, 2304, 768, 49,
      nullptr, nullptr, nullptr);
  attn_spatial<<<dim3(64, 12), blk512, 0, stream>>>(qkvbuf, attnbuf);
  gemmU<false, true, true, false><<<dim3(98 * 6), blk, 0, stream>>>(
      attnbuf, projsT, proj_b_s, x, x1, nullptr, 768, 768, 98 * 6, 6,
      nullptr, nullptr, nullptr);

  // stage 2: temporal
  ln_kernel<<<3136, blk, 0, stream>>>(x1, ln_t_g, ln_t_b, lnbuf);
  gemm8p<false, true, false, true><<<dim3(49 * 9), blk512, 0, stream>>>(
      lnbuf, qkvtT, qkv_b_t, nullptr, nullptr, qkvbuf, 2304, 768, 49,
      nullptr, nullptr, nullptr);
  attn_temporal<<<4704, blk, 0, stream>>>(qkvbuf, attnbuf);
  gemmU<false, true, true, false><<<dim3(98 * 6), blk, 0, stream>>>(
      attnbuf, projtT, proj_b_t, x1, out, nullptr, 768, 768, 98 * 6, 6,
      nullptr, nullptr, nullptr);

  // stage 3: MoE MLP
  ln_kernel<<<3136, blk, 0, stream>>>(out, ln_m_g, ln_m_b, lnbuf);
  sort_moe<<<1, blk, 0, stream>>>(expert_ids, perm, descs, meta);
  gemm8p<true, false, false, true><<<dim3(56, 6), blk512, 0, stream>>>(
      lnbuf, guT, nullptr, nullptr, nullptr, qkvbuf, 1536, 768, 0,
      perm, descs, meta);
  silu_mul<<<9408, blk, 0, stream>>>(qkvbuf, lnbuf);
  gemm8p<true, false, true, false><<<dim3(56, 3), blk512, 0, stream>>>(
      lnbuf, downT, nullptr, out, out, nullptr, 768, 768, 0,
      perm, descs, meta);
}

// Round 7
// 409.802 us; speedup vs baseline: 1.2939x; 1.0027x over previous
//
#include <hip/hip_runtime.h>

typedef __bf16 bf16;
typedef bf16 bf16x8 __attribute__((ext_vector_type(8)));
typedef float f32x4 __attribute__((ext_vector_type(4)));

#define BB 8
#define TT 8
#define SS 196
#define NTOK 1568           // T*S
#define ROWS 12544          // B*NTOK
#define HH 768
#define HD 64

__device__ __forceinline__ void gload16(const void* g, void* l) {
  __builtin_amdgcn_global_load_lds(
      (const __attribute__((address_space(1))) void*)g,
      (__attribute__((address_space(3))) void*)l, 16, 0, 0);
}

#define VMC4() asm volatile("s_waitcnt vmcnt(4)" ::: "memory")
#define VMC0() asm volatile("s_waitcnt vmcnt(0)" ::: "memory")
// phase sync: barrier, then drain ds_reads, then fence scheduler (rule #18)
#define PRE_MFMA() do { asm volatile("" ::: "memory");                      \
    __builtin_amdgcn_s_barrier();                                           \
    asm volatile("s_waitcnt lgkmcnt(0)" ::: "memory");                      \
    __builtin_amdgcn_sched_barrier(0); } while (0)
#define POST_MFMA() do { asm volatile("" ::: "memory");                     \
    __builtin_amdgcn_s_barrier(); asm volatile("" ::: "memory"); } while (0)

// ---------------- weight transpose f32[K][N] -> bf16[N][K], z-batched -------
__global__ __launch_bounds__(256)
void transpose_w(const float* __restrict__ in, bf16* __restrict__ out, int K, int N) {
  in  += (size_t)blockIdx.z * K * N;
  out += (size_t)blockIdx.z * K * N;
  __shared__ float tile[64][65];
  const int k0 = blockIdx.x * 64, n0 = blockIdx.y * 64;
  const int tx = threadIdx.x & 63, ty = threadIdx.x >> 6;
  #pragma unroll
  for (int rr = ty; rr < 64; rr += 4)
    tile[rr][tx] = in[(size_t)(k0 + rr) * N + n0 + tx];
  __syncthreads();
  #pragma unroll
  for (int rr = ty; rr < 64; rr += 4)
    out[(size_t)(n0 + rr) * K + k0 + tx] = (bf16)tile[tx][rr];
}

// gate_up transpose with column permutation: out row r <- src col pi(r):
// s = r>>6, off = r&63; pi = off<32 ? s*32+off : 768 + s*32 + off-32.
// So each 64-row stripe of guT = 32 gate rows + their 32 matching up rows.
__global__ __launch_bounds__(256)
void transpose_gu(const float* __restrict__ in, bf16* __restrict__ out) {
  const int K = 768, N = 1536;
  in  += (size_t)blockIdx.z * K * N;
  out += (size_t)blockIdx.z * K * N;
  __shared__ float tile[64][65];
  const int k0 = blockIdx.x * 64, n0 = blockIdx.y * 64;
  const int tx = threadIdx.x & 63, ty = threadIdx.x >> 6;
  const int s = n0 >> 6;
  #pragma unroll
  for (int rr = ty; rr < 64; rr += 4) {
    const int src = (tx < 32) ? (s * 32 + tx) : (768 + s * 32 + tx - 32);
    tile[rr][tx] = in[(size_t)(k0 + rr) * N + src];
  }
  __syncthreads();
  #pragma unroll
  for (int rr = ty; rr < 64; rr += 4)
    out[(size_t)(n0 + rr) * K + k0 + tx] = (bf16)tile[tx][rr];
}

// ---------------- layernorm: f32 in -> bf16 out, wave per row ---------------
__global__ __launch_bounds__(256)
void ln_kernel(const float* __restrict__ x, const float* __restrict__ g,
               const float* __restrict__ b, bf16* __restrict__ out) {
  const int row = blockIdx.x * 4 + (threadIdx.x >> 6);
  const int lane = threadIdx.x & 63;
  const float* xr = x + (size_t)row * HH;
  float v[12];
  float sum = 0.f, sq = 0.f;
  #pragma unroll
  for (int i = 0; i < 12; ++i) {
    v[i] = xr[lane + i * 64];
    sum += v[i];
    sq += v[i] * v[i];
  }
  #pragma unroll
  for (int off = 32; off > 0; off >>= 1) {
    sum += __shfl_xor(sum, off);
    sq  += __shfl_xor(sq, off);
  }
  const float mean = sum * (1.f / 768.f);
  const float var = sq * (1.f / 768.f) - mean * mean;
  const float inv = rsqrtf(var + 1e-6f);
  bf16* op = out + (size_t)row * HH;
  #pragma unroll
  for (int i = 0; i < 12; ++i) {
    const int c = lane + i * 64;
    op[c] = (bf16)((v[i] - mean) * inv * g[c] + b[c]);
  }
}

// ---------------- 8-phase 256x256 GEMM, m201-faithful schedule --------------
// 512 thr = 8 waves (2M x 4N), wave tile 128x64, BK=64, 2 K-tiles/iter.
// LDS 128KB: dbuf0 = even kt, dbuf1 = odd kt; each = A[256x64] + B[256x64].
// Quadrant order per K-tile: (qm0,qn0)(qm0,qn1)(qm1,qn1)(qm1,qn0) — A LDS
// reads end p3, B LDS reads end p2 (qn0 held in regs for p4).
// Stage slots (1 half = 128 rows x 64, 2 gload16/thread):
//   p1:A0(2i+1) p2:A1(2i+1) p3:B0(2i+2) p4:B1(2i+2)
//   p5:A0(2i+2) p6:A1(2i+2) p7:B0(2i+3) p8:B1(2i+3)
// vmcnt(4) at p4 (proves kt2i+1 landed: its halves are >=4 slots old) and at
// p8 (proves kt2i+2). Last iter: p4 -> vmcnt(0), stages for kt>=2NI skipped.
// Phase = {ds_read || stage -> barrier -> lgkmcnt(0)+sched_barrier ->
// setprio(1) 16 MFMA setprio(0) -> barrier}.
template<bool MOE, bool BIAS, bool RESID, bool OBF16, bool GUFUSE>
__global__ __launch_bounds__(512, 1)
void gemm8p(const bf16* __restrict__ A, const bf16* __restrict__ BT,
            const float* __restrict__ bias, const float* __restrict__ resid,
            float* __restrict__ outF, bf16* __restrict__ outB,
            int N, int K, int NMT,
            const int* __restrict__ perm, const int4* __restrict__ descs,
            const int* __restrict__ meta) {
  __shared__ __align__(16) bf16 lds[2 * 32768];   // 128 KB
  __shared__ int rowLds[256];

  const int tid = threadIdx.x;
  int M0 = 0, N0, ncnt = 32;
  if constexpr (MOE) {
    if ((int)blockIdx.x >= meta[0]) return;
    int4 d = descs[blockIdx.x];
    BT += (size_t)d.x * N * K;
    ncnt = d.z;
    N0 = blockIdx.y * 256;
    if (tid < 256) {
      const int nl = tid >> 3, b = tid & 7;
      const int n = perm[d.y + (nl < ncnt ? nl : ncnt - 1)];
      rowLds[tid] = b * NTOK + n;
    }
    __syncthreads();
  } else {
    const int G = gridDim.x;
    const int q = G >> 3, r = G & 7, xcd = blockIdx.x & 7, pos = blockIdx.x >> 3;
    const int work = (xcd < r ? xcd * (q + 1) : r * (q + 1) + (xcd - r) * q) + pos;
    const int mt = work % NMT, nt = work / NMT;
    M0 = mt * 256;
    N0 = nt * 256;
  }

  const int w = tid >> 6, lane = tid & 63;
  const int wr = w >> 2, wc = w & 3;
  const int lr = lane & 15, lg = lane >> 4;

  // staging: thread covers chunks tid, tid+512 of a 128-row half; LDS chunk
  // c holds src seg (c&7)^(row&7)  (rule #21: linear dest, swizzled source).
  const int srow0 = tid >> 3;            // 0..63
  const int srow1 = 64 + srow0;
  const int sseg0 = (tid & 7) ^ (srow0 & 7);
  int ar00, ar01, ar10, ar11;
  if constexpr (MOE) {
    ar00 = rowLds[srow0];        ar01 = rowLds[srow1];
    ar10 = rowLds[128 + srow0];  ar11 = rowLds[128 + srow1];
  } else {
    ar00 = M0 + srow0;           ar01 = M0 + srow1;
    ar10 = M0 + 128 + srow0;     ar11 = M0 + 128 + srow1;
  }
  const bf16* aP00 = A + (size_t)ar00 * K + sseg0 * 8;
  const bf16* aP01 = A + (size_t)ar01 * K + sseg0 * 8;
  const bf16* aP10 = A + (size_t)ar10 * K + sseg0 * 8;
  const bf16* aP11 = A + (size_t)ar11 * K + sseg0 * 8;
  const bf16* bP00 = BT + (size_t)(N0 + srow0) * K + sseg0 * 8;
  const bf16* bP01 = BT + (size_t)(N0 + srow1) * K + sseg0 * 8;
  const bf16* bP10 = BT + (size_t)(N0 + 128 + srow0) * K + sseg0 * 8;
  const bf16* bP11 = BT + (size_t)(N0 + 128 + srow1) * K + sseg0 * 8;

  auto STG = [&](const bf16* P0, const bf16* P1, int dstoff, int kt) {
    gload16(P0 + (size_t)kt * 64, lds + dstoff + tid * 8);
    gload16(P1 + (size_t)kt * 64, lds + dstoff + 4096 + tid * 8);
  };
  auto LDA = [&](int dd, int qm, bf16x8* D) {
    #pragma unroll
    for (int mf = 0; mf < 4; ++mf) {
      const int ra = wr * 128 + qm * 64 + mf * 16 + lr;
      const bf16* p = lds + dd * 32768 + ra * 64;
      D[mf * 2 + 0] = *(const bf16x8*)(p + ((lg ^ (lr & 7)) * 8));
      D[mf * 2 + 1] = *(const bf16x8*)(p + (((4 + lg) ^ (lr & 7)) * 8));
    }
  };
  auto LDB = [&](int dd, int qn, bf16x8* D) {
    #pragma unroll
    for (int nf = 0; nf < 2; ++nf) {
      const int rb = wc * 64 + qn * 32 + nf * 16 + lr;
      const bf16* p = lds + dd * 32768 + 16384 + rb * 64;
      D[nf * 2 + 0] = *(const bf16x8*)(p + ((lg ^ (lr & 7)) * 8));
      D[nf * 2 + 1] = *(const bf16x8*)(p + (((4 + lg) ^ (lr & 7)) * 8));
    }
  };

  f32x4 acc[8][4] = {};
  auto MM = [&](const bf16x8* AF, const bf16x8* BF, int qm, int qn) {
    __builtin_amdgcn_s_setprio(1);
    #pragma unroll
    for (int mf = 0; mf < 4; ++mf)
      #pragma unroll
      for (int nf = 0; nf < 2; ++nf) {
        f32x4 c = acc[qm * 4 + mf][qn * 2 + nf];
        c = __builtin_amdgcn_mfma_f32_16x16x32_bf16(AF[mf * 2 + 0], BF[nf * 2 + 0], c, 0, 0, 0);
        c = __builtin_amdgcn_mfma_f32_16x16x32_bf16(AF[mf * 2 + 1], BF[nf * 2 + 1], c, 0, 0, 0);
        acc[qm * 4 + mf][qn * 2 + nf] = c;
      }
    __builtin_amdgcn_s_setprio(0);
  };

  const int NI = K >> 7;   // K % 128 == 0

  // prologue: kt0 (A0,A1,B0,B1) + kt1 (B0,B1); vmcnt(4) -> kt0 landed.
  STG(aP00, aP01, 0, 0);
  STG(aP10, aP11, 8192, 0);
  STG(bP00, bP01, 16384, 0);
  STG(bP10, bP11, 24576, 0);
  STG(bP00, bP01, 32768 + 16384, 1);
  STG(bP10, bP11, 32768 + 24576, 1);
  VMC4();
  asm volatile("" ::: "memory");
  __builtin_amdgcn_s_barrier();
  asm volatile("" ::: "memory");

  bf16x8 a[8], b0[4], b1[4];
  for (int i = 0; i < NI; ++i) {
    const bool more = (i + 1 < NI);
    const int k1 = 2 * i + 1, k2 = 2 * i + 2, k3 = 2 * i + 3;
    // p1: kt2i (qm0,qn0) | stage A0(k1)->dbuf1
    LDA(0, 0, a); LDB(0, 0, b0);
    STG(aP00, aP01, 32768, k1);
    PRE_MFMA(); MM(a, b0, 0, 0); POST_MFMA();
    // p2: (qm0,qn1) | stage A1(k1)
    LDB(0, 1, b1);
    STG(aP10, aP11, 32768 + 8192, k1);
    PRE_MFMA(); MM(a, b1, 0, 1); POST_MFMA();
    // p3: (qm1,qn1) | stage B0(k2)->dbuf0  (dbuf0.B LDS reads ended p2)
    LDA(0, 1, a);
    if (more) STG(bP00, bP01, 16384, k2);
    PRE_MFMA(); MM(a, b1, 1, 1); POST_MFMA();
    // p4: (qm1,qn0) from regs | stage B1(k2); guard kt1
    if (more) STG(bP10, bP11, 24576, k2);
    if (more) { VMC4(); } else { VMC0(); }
    PRE_MFMA(); MM(a, b0, 1, 0); POST_MFMA();
    // p5: kt2i+1 (qm0,qn0) | stage A0(k2)  (dbuf0.A reads ended p3)
    LDA(1, 0, a); LDB(1, 0, b0);
    if (more) STG(aP00, aP01, 0, k2);
    PRE_MFMA(); MM(a, b0, 0, 0); POST_MFMA();
    // p6: (qm0,qn1) | stage A1(k2)
    LDB(1, 1, b1);
    if (more) STG(aP10, aP11, 8192, k2);
    PRE_MFMA(); MM(a, b1, 0, 1); POST_MFMA();
    // p7: (qm1,qn1) | stage B0(k3)->dbuf1 (dbuf1.B reads ended p6)
    LDA(1, 1, a);
    if (more) STG(bP00, bP01, 32768 + 16384, k3);
    PRE_MFMA(); MM(a, b1, 1, 1); POST_MFMA();
    // p8: (qm1,qn0) | stage B1(k3); guard kt2i+2
    if (more) STG(bP10, bP11, 32768 + 24576, k3);
    if (more) { VMC4(); }
    PRE_MFMA(); MM(a, b0, 1, 0); POST_MFMA();
  }

  #pragma unroll
  for (int m = 0; m < 8; ++m) {
    #pragma unroll
    for (int j = 0; j < 4; ++j) {
      const int r = wr * 128 + m * 16 + lg * 4 + j;
      if (MOE && ((r >> 3) >= ncnt)) continue;
      const size_t grow = MOE ? (size_t)rowLds[r] : (size_t)(M0 + r);
      if constexpr (GUFUSE) {
        // acc[m][0..1] = gate cols, acc[m][2..3] = matching up cols (in-lane)
        const size_t rbase = grow * 768;
        #pragma unroll
        for (int n = 0; n < 2; ++n) {
          const int icol = (N0 >> 1) + wc * 32 + n * 16 + lr;
          const float g = acc[m][n][j], u = acc[m][n + 2][j];
          outB[rbase + icol] = (bf16)(g / (1.f + __expf(-g)) * u);
        }
      } else {
        const size_t rbase = grow * N;
        #pragma unroll
        for (int n = 0; n < 4; ++n) {
          const int gcol = N0 + wc * 64 + n * 16 + lr;
          float v = acc[m][n][j];
          if constexpr (BIAS)  v += bias[gcol];
          if constexpr (RESID) v += resid[rbase + gcol];
          if constexpr (OBF16) outB[rbase + gcol] = (bf16)v;
          else                 outF[rbase + gcol] = v;
        }
      }
    }
  }
}

// ---------------- 2-phase 128x128 GEMM (proj: N=768) ------------------------
template<bool BIAS, bool RESID, bool OBF16>
__global__ __launch_bounds__(256, 2)
void gemmU(const bf16* __restrict__ A, const bf16* __restrict__ BT,
           const float* __restrict__ bias, const float* __restrict__ resid,
           float* __restrict__ outF, bf16* __restrict__ outB,
           int N, int K, int G, int NTN) {
  __shared__ __align__(16) bf16 lds[3 * 8192];

  const int tid = threadIdx.x;
  int M0, N0;
  {
    const int id = blockIdx.x;
    const int q = G >> 3, r = G & 7, xcd = id & 7, pos = id >> 3;
    const int work = (xcd < r ? xcd * (q + 1) : r * (q + 1) + (xcd - r) * q) + pos;
    const int mt = work / NTN, nt = work - mt * NTN;
    M0 = mt * 128;
    N0 = nt * 128;
  }

  const int w = tid >> 6, lane = tid & 63;
  const int wr = w >> 1, wc = w & 1;

  size_t aG[2], bG[2]; int aL[2], bL[2];
  #pragma unroll
  for (int i = 0; i < 2; ++i) {
    const int c = tid + i * 256;
    const int row = c >> 2, seg = (c & 3) ^ ((c >> 3) & 3);
    aG[i] = (size_t)(M0 + row) * K + seg * 8;
    aL[i] = c * 8;
    bG[i] = (size_t)(N0 + row) * K + seg * 8;
    bL[i] = 4096 + c * 8;
  }

#define STGU(tt) { bf16* bp = lds + ((tt) % 3) * 8192; const int ko = (tt) << 5; \
    gload16(A + aG[0] + ko, bp + aL[0]);                                        \
    gload16(A + aG[1] + ko, bp + aL[1]);                                        \
    gload16(BT + bG[0] + ko, bp + bL[0]);                                       \
    gload16(BT + bG[1] + ko, bp + bL[1]); }

  STGU(0);
  STGU(1);

  f32x4 acc[4][4] = {};
  const int lr = lane & 15, lg = lane >> 4;
  const int xr = ((lr >> 1) & 3) * 8;
  const int NT = K >> 5;

  for (int t = 0; t < NT; ++t) {
    if (t + 1 < NT) { asm volatile("s_waitcnt vmcnt(4)" ::: "memory"); }
    else            { asm volatile("s_waitcnt vmcnt(0)" ::: "memory"); }
    __builtin_amdgcn_s_barrier();
    asm volatile("" ::: "memory");

    const bf16* Ab = lds + (t % 3) * 8192;
    const bf16* Bb = Ab + 4096;
    bf16x8 af[4], bf_[4];
    #pragma unroll
    for (int m = 0; m < 4; ++m)
      af[m] = *(const bf16x8*)&Ab[(wr * 64 + m * 16 + lr) * 32 + ((lg * 8) ^ xr)];
    #pragma unroll
    for (int n = 0; n < 4; ++n)
      bf_[n] = *(const bf16x8*)&Bb[(wc * 64 + n * 16 + lr) * 32 + ((lg * 8) ^ xr)];

    __builtin_amdgcn_s_setprio(1);
    #pragma unroll
    for (int m = 0; m < 4; ++m)
      #pragma unroll
      for (int n = 0; n < 4; ++n)
        acc[m][n] = __builtin_amdgcn_mfma_f32_16x16x32_bf16(af[m], bf_[n], acc[m][n], 0, 0, 0);
    __builtin_amdgcn_s_setprio(0);

    asm volatile("" ::: "memory");
    __builtin_amdgcn_s_barrier();
    asm volatile("" ::: "memory");
    if (t + 2 < NT) STGU(t + 2);
  }
#undef STGU

  #pragma unroll
  for (int m = 0; m < 4; ++m) {
    #pragma unroll
    for (int j = 0; j < 4; ++j) {
      const int r = wr * 64 + m * 16 + lg * 4 + j;
      const size_t rbase = (size_t)(M0 + r) * N;
      #pragma unroll
      for (int n = 0; n < 4; ++n) {
        const int gcol = N0 + wc * 64 + n * 16 + lr;
        float v = acc[m][n][j];
        if constexpr (BIAS)  v += bias[gcol];
        if constexpr (RESID) v += resid[rbase + gcol];
        if constexpr (OBF16) outB[rbase + gcol] = (bf16)v;
        else                 outF[rbase + gcol] = v;
      }
    }
  }
}

// ---------------- spatial attention (MFMA): block per (bp, h), 8 waves ------
#define SPAD 208
#define VST 232
__global__ __launch_bounds__(512)
void attn_spatial(const bf16* __restrict__ qkv, bf16* __restrict__ out) {
  __shared__ __align__(16) bf16 Ks[SPAD * 64];
  __shared__ __align__(16) bf16 Vt[64 * VST];
  __shared__ __align__(16) bf16 Pb[8][16 * VST];

  const int bp = blockIdx.x, h = blockIdx.y;
  const int tid = threadIdx.x;
  const int w = tid >> 6, lane = tid & 63;
  const int lr = lane & 15, lg = lane >> 4;
  const size_t base = (size_t)bp * SS * 2304 + h * HD;

  for (int cb = w * 64; cb < SPAD * 8; cb += 512) {
    const int c = cb + lane;
    const int row = c >> 3, seg = c & 7;
    const int srow = row < SS ? row : SS - 1;
    const int sseg = seg ^ (row & 7);
    gload16(qkv + base + (size_t)srow * 2304 + 768 + sseg * 8, Ks + cb * 8);
  }
  for (int t = tid; t < 224 * 8; t += 512) {
    const int k = t >> 3, dseg = t & 7;
    const int sk = k < SS ? k : SS - 1;
    bf16x8 v = *(const bf16x8*)(qkv + base + (size_t)sk * 2304 + 1536 + dseg * 8);
    #pragma unroll
    for (int i = 0; i < 8; ++i) Vt[(dseg * 8 + i) * VST + k] = v[i];
  }
  bf16* Pw = Pb[w];
  for (int i = lane; i < 256; i += 64)
    Pw[(i >> 4) * VST + 208 + (i & 15)] = (bf16)0.f;
  __syncthreads();

  for (int t = w; t < 13; t += 8) {
    const int q0 = t * 16;
    const int qr = q0 + lr;
    const bf16* qp = qkv + base + (size_t)(qr < SS ? qr : SS - 1) * 2304 + lg * 8;
    const bf16x8 af0 = *(const bf16x8*)qp;
    const bf16x8 af1 = *(const bf16x8*)(qp + 32);

    f32x4 sc[13];
    #pragma unroll
    for (int f = 0; f < 13; ++f) sc[f] = (f32x4){0.f, 0.f, 0.f, 0.f};
    #pragma unroll
    for (int f = 0; f < 13; ++f) {
      const int key = f * 16 + lr;
      const bf16x8 bv0 = *(const bf16x8*)&Ks[key * 64 + ((lg) ^ (key & 7)) * 8];
      const bf16x8 bv1 = *(const bf16x8*)&Ks[key * 64 + ((4 + lg) ^ (key & 7)) * 8];
      sc[f] = __builtin_amdgcn_mfma_f32_16x16x32_bf16(af0, bv0, sc[f], 0, 0, 0);
      sc[f] = __builtin_amdgcn_mfma_f32_16x16x32_bf16(af1, bv1, sc[f], 0, 0, 0);
    }
    #pragma unroll
    for (int f = 0; f < 13; ++f)
      #pragma unroll
      for (int j = 0; j < 4; ++j) sc[f][j] *= 0.125f;
    if (192 + lr >= SS)
      #pragma unroll
      for (int j = 0; j < 4; ++j) sc[12][j] = -1e30f;

    float mx[4], ls[4];
    #pragma unroll
    for (int j = 0; j < 4; ++j) {
      float m = sc[0][j];
      #pragma unroll
      for (int f = 1; f < 13; ++f) m = fmaxf(m, sc[f][j]);
      #pragma unroll
      for (int off = 1; off < 16; off <<= 1) m = fmaxf(m, __shfl_xor(m, off));
      mx[j] = m;
    }
    #pragma unroll
    for (int j = 0; j < 4; ++j) ls[j] = 0.f;
    #pragma unroll
    for (int f = 0; f < 13; ++f) {
      #pragma unroll
      for (int j = 0; j < 4; ++j) {
        const float p = __expf(sc[f][j] - mx[j]);
        ls[j] += p;
        Pw[(lg * 4 + j) * VST + f * 16 + lr] = (bf16)p;
      }
    }
    #pragma unroll
    for (int j = 0; j < 4; ++j) {
      #pragma unroll
      for (int off = 1; off < 16; off <<= 1) ls[j] += __shfl_xor(ls[j], off);
      ls[j] = 1.f / ls[j];
    }

    f32x4 oacc[4];
    #pragma unroll
    for (int n = 0; n < 4; ++n) oacc[n] = (f32x4){0.f, 0.f, 0.f, 0.f};
    #pragma unroll
    for (int kb = 0; kb < 7; ++kb) {
      const bf16x8 pa = *(const bf16x8*)&Pw[lr * VST + kb * 32 + lg * 8];
      #pragma unroll
      for (int n = 0; n < 4; ++n) {
        const bf16x8 bv = *(const bf16x8*)&Vt[(n * 16 + lr) * VST + kb * 32 + lg * 8];
        oacc[n] = __builtin_amdgcn_mfma_f32_16x16x32_bf16(pa, bv, oacc[n], 0, 0, 0);
      }
    }
    #pragma unroll
    for (int j = 0; j < 4; ++j) {
      const int row = q0 + lg * 4 + j;
      if (row < SS) {
        bf16* op = out + ((size_t)bp * SS + row) * 768 + h * HD;
        #pragma unroll
        for (int n = 0; n < 4; ++n) op[n * 16 + lr] = (bf16)(oacc[n][j] * ls[j]);
      }
    }
  }
}

// ---------------- temporal attention: wave per (b, s, h), T=8 ---------------
__global__ __launch_bounds__(256)
void attn_temporal(const bf16* __restrict__ qkv, bf16* __restrict__ out) {
  const int pair = blockIdx.x * 4 + (threadIdx.x >> 6);
  const int lane = threadIdx.x & 63;
  const int h = pair % 12;
  const int bs = pair / 12;
  const int b = bs / SS, s = bs - b * SS;
  const size_t row0 = (size_t)b * NTOK + s;
  const int q = lane >> 3, k = lane & 7;
  const bf16* qr = qkv + (row0 + (size_t)q * SS) * 2304 + h * HD;
  const bf16* kr = qkv + (row0 + (size_t)k * SS) * 2304 + 768 + h * HD;
  float sc = 0.f;
  #pragma unroll
  for (int j = 0; j < 8; ++j) {
    bf16x8 qv = ((const bf16x8*)qr)[j];
    bf16x8 kv = ((const bf16x8*)kr)[j];
    #pragma unroll
    for (int d = 0; d < 8; ++d) sc += (float)qv[d] * (float)kv[d];
  }
  sc *= 0.125f;
  float mxv = sc;
  #pragma unroll
  for (int off = 1; off < 8; off <<= 1) mxv = fmaxf(mxv, __shfl_xor(mxv, off));
  float p = __expf(sc - mxv);
  float sum = p;
  #pragma unroll
  for (int off = 1; off < 8; off <<= 1) sum += __shfl_xor(sum, off);
  p /= sum;

  const int dg = lane & 7;
  float o[8] = {0, 0, 0, 0, 0, 0, 0, 0};
  #pragma unroll
  for (int kk = 0; kk < 8; ++kk) {
    const float pk = __shfl(p, (lane & 56) + kk);
    const bf16* vr = qkv + (row0 + (size_t)kk * SS) * 2304 + 1536 + h * HD + dg * 8;
    bf16x8 vv = *(const bf16x8*)vr;
    #pragma unroll
    for (int j = 0; j < 8; ++j) o[j] += pk * (float)vv[j];
  }
  bf16* op = out + (row0 + (size_t)q * SS) * 768 + h * HD + dg * 8;
  bf16x8 ov;
  #pragma unroll
  for (int j = 0; j < 8; ++j) ov[j] = (bf16)o[j];
  *(bf16x8*)op = ov;
}

// ---------------- MoE: bucket n-indices by expert + 32-token descriptors ----
__global__ __launch_bounds__(256)
void sort_moe(const int* __restrict__ eids, int* __restrict__ perm,
              int4* __restrict__ descs, int* __restrict__ meta) {
  __shared__ int cnt[4], base[4], cur[4];
  const int tid = threadIdx.x;
  if (tid < 4) cnt[tid] = 0;
  __syncthreads();
  for (int n = tid; n < NTOK; n += 256) atomicAdd(&cnt[eids[n]], 1);
  __syncthreads();
  if (tid == 0) {
    int off = 0;
    for (int e = 0; e < 4; ++e) { base[e] = off; cur[e] = off; off += cnt[e]; }
  }
  __syncthreads();
  for (int n = tid; n < NTOK; n += 256) {
    const int pos = atomicAdd(&cur[eids[n]], 1);
    perm[pos] = n;
  }
  if (tid == 0) {
    int t = 0;
    for (int e = 0; e < 4; ++e)
      for (int st = 0; st < cnt[e]; st += 32) {
        const int c = cnt[e] - st;
        descs[t++] = make_int4(e, base[e] + st, c < 32 ? c : 32, 0);
      }
    meta[0] = t;
  }
}

// ---------------- launch ------------------------------------------------------
extern "C" void kernel_launch(void* const* d_in, const int* in_sizes, int n_in,
                              void* d_out, int out_size, void* d_ws, size_t ws_size,
                              hipStream_t stream) {
  (void)in_sizes; (void)n_in; (void)out_size; (void)ws_size;
  const float* x        = (const float*)d_in[0];
  const float* qkv_w_s  = (const float*)d_in[1];
  const float* qkv_b_s  = (const float*)d_in[2];
  const float* proj_w_s = (const float*)d_in[3];
  const float* proj_b_s = (const float*)d_in[4];
  const float* qkv_w_t  = (const float*)d_in[5];
  const float* qkv_b_t  = (const float*)d_in[6];
  const float* proj_w_t = (const float*)d_in[7];
  const float* proj_b_t = (const float*)d_in[8];
  const float* ln_s_g   = (const float*)d_in[9];
  const float* ln_s_b   = (const float*)d_in[10];
  const float* ln_t_g   = (const float*)d_in[11];
  const float* ln_t_b   = (const float*)d_in[12];
  const float* ln_m_g   = (const float*)d_in[13];
  const float* ln_m_b   = (const float*)d_in[14];
  const float* gate_up  = (const float*)d_in[15];
  const float* down_w   = (const float*)d_in[16];
  const int* expert_ids = (const int*)d_in[19];
  float* out = (float*)d_out;

  char* ws = (char*)d_ws;
  bf16* qkvsT   = (bf16*)(ws + 0);
  bf16* projsT  = (bf16*)(ws + 3538944);
  bf16* qkvtT   = (bf16*)(ws + 4718592);
  bf16* projtT  = (bf16*)(ws + 8257536);
  bf16* guT     = (bf16*)(ws + 9437184);
  bf16* downT   = (bf16*)(ws + 18874368);
  bf16* lnbuf   = (bf16*)(ws + 23592960);
  bf16* qkvbuf  = (bf16*)(ws + 42860544);   // qkv / inter buffer
  bf16* attnbuf = (bf16*)(ws + 100663296);
  float* x1     = (float*)(ws + 119930880);
  int*  perm    = (int*)(ws + 158466048);
  int4* descs   = (int4*)(ws + 158472320);
  int*  meta    = (int*)(ws + 158473952);

  const dim3 blk(256);
  const dim3 blk512(512);

  transpose_w<<<dim3(12, 36, 1), blk, 0, stream>>>(qkv_w_s, qkvsT, 768, 2304);
  transpose_w<<<dim3(12, 12, 1), blk, 0, stream>>>(proj_w_s, projsT, 768, 768);
  transpose_w<<<dim3(12, 36, 1), blk, 0, stream>>>(qkv_w_t, qkvtT, 768, 2304);
  transpose_w<<<dim3(12, 12, 1), blk, 0, stream>>>(proj_w_t, projtT, 768, 768);
  transpose_gu<<<dim3(12, 24, 4), blk, 0, stream>>>(gate_up, guT);
  transpose_w<<<dim3(12, 12, 4), blk, 0, stream>>>(down_w, downT, 768, 768);

  // stage 1: spatial
  ln_kernel<<<3136, blk, 0, stream>>>(x, ln_s_g, ln_s_b, lnbuf);
  gemm8p<false, true, false, true, false><<<dim3(49 * 9), blk512, 0, stream>>>(
      lnbuf, qkvsT, qkv_b_s, nullptr, nullptr, qkvbuf, 2304, 768, 49,
      nullptr, nullptr, nullptr);
  attn_spatial<<<dim3(64, 12), blk512, 0, stream>>>(qkvbuf, attnbuf);
  gemmU<true, true, false><<<dim3(98 * 6), blk, 0, stream>>>(
      attnbuf, projsT, proj_b_s, x, x1, nullptr, 768, 768, 98 * 6, 6);

  // stage 2: temporal
  ln_kernel<<<3136, blk, 0, stream>>>(x1, ln_t_g, ln_t_b, lnbuf);
  gemm8p<false, true, false, true, false><<<dim3(49 * 9), blk512, 0, stream>>>(
      lnbuf, qkvtT, qkv_b_t, nullptr, nullptr, qkvbuf, 2304, 768, 49,
      nullptr, nullptr, nullptr);
  attn_temporal<<<4704, blk, 0, stream>>>(qkvbuf, attnbuf);
  gemmU<true, true, false><<<dim3(98 * 6), blk, 0, stream>>>(
      attnbuf, projtT, proj_b_t, x1, out, nullptr, 768, 768, 98 * 6, 6);

  // stage 3: MoE MLP (silu fused into gate_up epilogue; inter in qkvbuf)
  ln_kernel<<<3136, blk, 0, stream>>>(out, ln_m_g, ln_m_b, lnbuf);
  sort_moe<<<1, blk, 0, stream>>>(expert_ids, perm, descs, meta);
  gemm8p<true, false, false, true, true><<<dim3(56, 6), blk512, 0, stream>>>(
      lnbuf, guT, nullptr, nullptr, nullptr, qkvbuf, 1536, 768, 0,
      perm, descs, meta);
  gemm8p<true, false, true, false, false><<<dim3(56, 3), blk512, 0, stream>>>(
      qkvbuf, downT, nullptr, out, out, nullptr, 768, 768, 0,
      perm, descs, meta);
}

// Round 8
// 396.412 us; speedup vs baseline: 1.3376x; 1.0338x over previous
//
#include <hip/hip_runtime.h>

typedef __bf16 bf16;
typedef bf16 bf16x8 __attribute__((ext_vector_type(8)));
typedef float f32x4 __attribute__((ext_vector_type(4)));

#define BB 8
#define TT 8
#define SS 196
#define NTOK 1568           // T*S
#define ROWS 12544          // B*NTOK
#define HH 768
#define HD 64

__device__ __forceinline__ void gload16(const void* g, void* l) {
  __builtin_amdgcn_global_load_lds(
      (const __attribute__((address_space(1))) void*)g,
      (__attribute__((address_space(3))) void*)l, 16, 0, 0);
}

// ---------------- weight transpose f32[K][N] -> bf16[N][K], z-batched -------
__global__ __launch_bounds__(256)
void transpose_w(const float* __restrict__ in, bf16* __restrict__ out, int K, int N) {
  in  += (size_t)blockIdx.z * K * N;
  out += (size_t)blockIdx.z * K * N;
  __shared__ float tile[64][65];
  const int k0 = blockIdx.x * 64, n0 = blockIdx.y * 64;
  const int tx = threadIdx.x & 63, ty = threadIdx.x >> 6;
  #pragma unroll
  for (int rr = ty; rr < 64; rr += 4)
    tile[rr][tx] = in[(size_t)(k0 + rr) * N + n0 + tx];
  __syncthreads();
  #pragma unroll
  for (int rr = ty; rr < 64; rr += 4)
    out[(size_t)(n0 + rr) * K + k0 + tx] = (bf16)tile[tx][rr];
}

// gate_up transpose with column permutation: each 64-row stripe of guT =
// 32 gate rows + their 32 matching up rows (enables in-lane silu fusion).
__global__ __launch_bounds__(256)
void transpose_gu(const float* __restrict__ in, bf16* __restrict__ out) {
  const int K = 768, N = 1536;
  in  += (size_t)blockIdx.z * K * N;
  out += (size_t)blockIdx.z * K * N;
  __shared__ float tile[64][65];
  const int k0 = blockIdx.x * 64, n0 = blockIdx.y * 64;
  const int tx = threadIdx.x & 63, ty = threadIdx.x >> 6;
  const int s = n0 >> 6;
  #pragma unroll
  for (int rr = ty; rr < 64; rr += 4) {
    const int src = (tx < 32) ? (s * 32 + tx) : (768 + s * 32 + tx - 32);
    tile[rr][tx] = in[(size_t)(k0 + rr) * N + src];
  }
  __syncthreads();
  #pragma unroll
  for (int rr = ty; rr < 64; rr += 4)
    out[(size_t)(n0 + rr) * K + k0 + tx] = (bf16)tile[tx][rr];
}

// ---------------- layernorm: f32 in -> bf16 out, wave per row ---------------
__global__ __launch_bounds__(256)
void ln_kernel(const float* __restrict__ x, const float* __restrict__ g,
               const float* __restrict__ b, bf16* __restrict__ out) {
  const int row = blockIdx.x * 4 + (threadIdx.x >> 6);
  const int lane = threadIdx.x & 63;
  const float* xr = x + (size_t)row * HH;
  float v[12];
  float sum = 0.f, sq = 0.f;
  #pragma unroll
  for (int i = 0; i < 12; ++i) {
    v[i] = xr[lane + i * 64];
    sum += v[i];
    sq += v[i] * v[i];
  }
  #pragma unroll
  for (int off = 32; off > 0; off >>= 1) {
    sum += __shfl_xor(sum, off);
    sq  += __shfl_xor(sq, off);
  }
  const float mean = sum * (1.f / 768.f);
  const float var = sq * (1.f / 768.f) - mean * mean;
  const float inv = rsqrtf(var + 1e-6f);
  bf16* op = out + (size_t)row * HH;
  #pragma unroll
  for (int i = 0; i < 12; ++i) {
    const int c = lane + i * 64;
    op[c] = (bf16)((v[i] - mean) * inv * g[c] + b[c]);
  }
}

// ---------------- deep-pipe GEMM: 256x256, BK=32, 4 LDS bufs, 1 barrier/tile
// C[M,N] = A[M,K](bf16) * BT[N,K](bf16). 512 thr = 8 waves (2M x 4N), wave
// tile 128x64, acc[8][4]. LDS 128KB = 4 bufs x (A 256x32 + B 256x32).
// Phase t: vmcnt(8) -> barrier -> {12 ds_read_b128 (tile t, buf t&3) ||
// 4 gload_lds (tile t+3, buf (t+3)&3)} -> lgkmcnt(0)+sched_barrier ->
// setprio(1) 32 MFMA setprio(0).  24 barriers total (K=768), 32 MFMA each.
// Hazards: stage(t+3) overwrites buf[(t-1)&3]; every wave finished tile-(t-1)
// ds_reads at its iter-(t-1) lgkmcnt(0), before the iter-t barrier that
// precedes the stage => single barrier race-free. Issue->use gap = 3 phases.
// Tail: vmcnt 8 -> 4 -> 0. Chunk-XOR swizzle seg^((row>>1)&3) both sides
// (rule #21): 2 lanes/bank on ds_read = free.
// MOE: desc = 32 tokens x 8 batch = 256 gathered rows via rowLds.
template<bool MOE, bool BIAS, bool RESID, bool OBF16, bool GUFUSE>
__global__ __launch_bounds__(512, 1)
void gemmDP(const bf16* __restrict__ A, const bf16* __restrict__ BT,
            const float* __restrict__ bias, const float* __restrict__ resid,
            float* __restrict__ outF, bf16* __restrict__ outB,
            int N, int K, int NMT,
            const int* __restrict__ perm, const int4* __restrict__ descs,
            const int* __restrict__ meta) {
  __shared__ __align__(16) bf16 lds[4 * 16384];   // 128 KB
  __shared__ int rowLds[256];

  const int tid = threadIdx.x;
  int M0 = 0, N0, ncnt = 32;
  if constexpr (MOE) {
    if ((int)blockIdx.x >= meta[0]) return;
    int4 d = descs[blockIdx.x];
    BT += (size_t)d.x * N * K;
    ncnt = d.z;
    N0 = blockIdx.y * 256;
    if (tid < 256) {
      const int nl = tid >> 3, b = tid & 7;
      const int n = perm[d.y + (nl < ncnt ? nl : ncnt - 1)];
      rowLds[tid] = b * NTOK + n;
    }
    __syncthreads();
  } else {
    const int G = gridDim.x;
    const int q = G >> 3, r = G & 7, xcd = blockIdx.x & 7, pos = blockIdx.x >> 3;
    const int work = (xcd < r ? xcd * (q + 1) : r * (q + 1) + (xcd - r) * q) + pos;
    const int mt = work % NMT, nt = work / NMT;
    M0 = mt * 256;
    N0 = nt * 256;
  }

  const int w = tid >> 6, lane = tid & 63;
  const int wr = w >> 2, wc = w & 3;
  const int lr = lane & 15, lg = lane >> 4;

  // staging: thread covers chunk tid (rows 0..127) and tid+512 (rows 128..255)
  // of each 32-col K-tile; 4 chunks/row; src seg = (c&3)^((c>>3)&3).
  const int srow0 = tid >> 2;                       // 0..127
  const int sseg = ((tid & 3) ^ ((tid >> 3) & 3)) * 8;
  int arow0, arow1;
  if constexpr (MOE) {
    arow0 = rowLds[srow0];
    arow1 = rowLds[128 + srow0];
  } else {
    arow0 = M0 + srow0;
    arow1 = M0 + 128 + srow0;
  }
  const bf16* aQ0 = A + (size_t)arow0 * K + sseg;
  const bf16* aQ1 = A + (size_t)arow1 * K + sseg;
  const bf16* bQ0 = BT + (size_t)(N0 + srow0) * K + sseg;
  const bf16* bQ1 = BT + (size_t)(N0 + 128 + srow0) * K + sseg;

  auto STG = [&](int kt) {
    bf16* buf = lds + (kt & 3) * 16384;
    const int ko = kt << 5;
    gload16(aQ0 + ko, buf + tid * 8);
    gload16(aQ1 + ko, buf + 4096 + tid * 8);
    gload16(bQ0 + ko, buf + 8192 + tid * 8);
    gload16(bQ1 + ko, buf + 12288 + tid * 8);
  };

  const int axr = (lg ^ ((lr >> 1) & 3)) * 8;       // read-side chunk XOR

  f32x4 acc[8][4] = {};
  const int NT = K >> 5;                            // K % 32 == 0 (24 here)

  // prologue: stage tiles 0,1,2 (12 loads in flight)
  STG(0); STG(1); STG(2);

  for (int t = 0; t < NT; ++t) {
    if (t + 2 < NT)      { asm volatile("s_waitcnt vmcnt(8)" ::: "memory"); }
    else if (t + 1 < NT) { asm volatile("s_waitcnt vmcnt(4)" ::: "memory"); }
    else                 { asm volatile("s_waitcnt vmcnt(0)" ::: "memory"); }
    __builtin_amdgcn_s_barrier();
    asm volatile("" ::: "memory");

    const bf16* Ab = lds + (t & 3) * 16384;
    const bf16* Bb = Ab + 8192;
    bf16x8 a[8], b[4];
    #pragma unroll
    for (int mf = 0; mf < 8; ++mf) {
      const int row = wr * 128 + mf * 16 + lr;
      a[mf] = *(const bf16x8*)(Ab + row * 32 + axr);
    }
    #pragma unroll
    for (int nf = 0; nf < 4; ++nf) {
      const int row = wc * 64 + nf * 16 + lr;
      b[nf] = *(const bf16x8*)(Bb + row * 32 + axr);
    }
    if (t + 3 < NT) STG(t + 3);

    asm volatile("s_waitcnt lgkmcnt(0)" ::: "memory");
    __builtin_amdgcn_sched_barrier(0);
    __builtin_amdgcn_s_setprio(1);
    #pragma unroll
    for (int mf = 0; mf < 8; ++mf)
      #pragma unroll
      for (int nf = 0; nf < 4; ++nf)
        acc[mf][nf] = __builtin_amdgcn_mfma_f32_16x16x32_bf16(a[mf], b[nf], acc[mf][nf], 0, 0, 0);
    __builtin_amdgcn_s_setprio(0);
    asm volatile("" ::: "memory");
  }

  #pragma unroll
  for (int m = 0; m < 8; ++m) {
    #pragma unroll
    for (int j = 0; j < 4; ++j) {
      const int r = wr * 128 + m * 16 + lg * 4 + j;
      if (MOE && ((r >> 3) >= ncnt)) continue;
      const size_t grow = MOE ? (size_t)rowLds[r] : (size_t)(M0 + r);
      if constexpr (GUFUSE) {
        // acc[m][0..1] = gate cols, acc[m][2..3] = matching up cols (in-lane)
        const size_t rbase = grow * 768;
        #pragma unroll
        for (int n = 0; n < 2; ++n) {
          const int icol = (N0 >> 1) + wc * 32 + n * 16 + lr;
          const float g = acc[m][n][j], u = acc[m][n + 2][j];
          outB[rbase + icol] = (bf16)(g / (1.f + __expf(-g)) * u);
        }
      } else {
        const size_t rbase = grow * N;
        #pragma unroll
        for (int n = 0; n < 4; ++n) {
          const int gcol = N0 + wc * 64 + n * 16 + lr;
          float v = acc[m][n][j];
          if constexpr (BIAS)  v += bias[gcol];
          if constexpr (RESID) v += resid[rbase + gcol];
          if constexpr (OBF16) outB[rbase + gcol] = (bf16)v;
          else                 outF[rbase + gcol] = v;
        }
      }
    }
  }
}

// ---------------- spatial attention (MFMA): block per (bp, h), 8 waves ------
#define SPAD 208
#define VST 232
__global__ __launch_bounds__(512)
void attn_spatial(const bf16* __restrict__ qkv, bf16* __restrict__ out) {
  __shared__ __align__(16) bf16 Ks[SPAD * 64];
  __shared__ __align__(16) bf16 Vt[64 * VST];
  __shared__ __align__(16) bf16 Pb[8][16 * VST];

  const int bp = blockIdx.x, h = blockIdx.y;
  const int tid = threadIdx.x;
  const int w = tid >> 6, lane = tid & 63;
  const int lr = lane & 15, lg = lane >> 4;
  const size_t base = (size_t)bp * SS * 2304 + h * HD;

  for (int cb = w * 64; cb < SPAD * 8; cb += 512) {
    const int c = cb + lane;
    const int row = c >> 3, seg = c & 7;
    const int srow = row < SS ? row : SS - 1;
    const int sseg = seg ^ (row & 7);
    gload16(qkv + base + (size_t)srow * 2304 + 768 + sseg * 8, Ks + cb * 8);
  }
  for (int t = tid; t < 224 * 8; t += 512) {
    const int k = t >> 3, dseg = t & 7;
    const int sk = k < SS ? k : SS - 1;
    bf16x8 v = *(const bf16x8*)(qkv + base + (size_t)sk * 2304 + 1536 + dseg * 8);
    #pragma unroll
    for (int i = 0; i < 8; ++i) Vt[(dseg * 8 + i) * VST + k] = v[i];
  }
  bf16* Pw = Pb[w];
  for (int i = lane; i < 256; i += 64)
    Pw[(i >> 4) * VST + 208 + (i & 15)] = (bf16)0.f;
  __syncthreads();

  for (int t = w; t < 13; t += 8) {
    const int q0 = t * 16;
    const int qr = q0 + lr;
    const bf16* qp = qkv + base + (size_t)(qr < SS ? qr : SS - 1) * 2304 + lg * 8;
    const bf16x8 af0 = *(const bf16x8*)qp;
    const bf16x8 af1 = *(const bf16x8*)(qp + 32);

    f32x4 sc[13];
    #pragma unroll
    for (int f = 0; f < 13; ++f) sc[f] = (f32x4){0.f, 0.f, 0.f, 0.f};
    #pragma unroll
    for (int f = 0; f < 13; ++f) {
      const int key = f * 16 + lr;
      const bf16x8 bv0 = *(const bf16x8*)&Ks[key * 64 + ((lg) ^ (key & 7)) * 8];
      const bf16x8 bv1 = *(const bf16x8*)&Ks[key * 64 + ((4 + lg) ^ (key & 7)) * 8];
      sc[f] = __builtin_amdgcn_mfma_f32_16x16x32_bf16(af0, bv0, sc[f], 0, 0, 0);
      sc[f] = __builtin_amdgcn_mfma_f32_16x16x32_bf16(af1, bv1, sc[f], 0, 0, 0);
    }
    #pragma unroll
    for (int f = 0; f < 13; ++f)
      #pragma unroll
      for (int j = 0; j < 4; ++j) sc[f][j] *= 0.125f;
    if (192 + lr >= SS)
      #pragma unroll
      for (int j = 0; j < 4; ++j) sc[12][j] = -1e30f;

    float mx[4], ls[4];
    #pragma unroll
    for (int j = 0; j < 4; ++j) {
      float m = sc[0][j];
      #pragma unroll
      for (int f = 1; f < 13; ++f) m = fmaxf(m, sc[f][j]);
      #pragma unroll
      for (int off = 1; off < 16; off <<= 1) m = fmaxf(m, __shfl_xor(m, off));
      mx[j] = m;
    }
    #pragma unroll
    for (int j = 0; j < 4; ++j) ls[j] = 0.f;
    #pragma unroll
    for (int f = 0; f < 13; ++f) {
      #pragma unroll
      for (int j = 0; j < 4; ++j) {
        const float p = __expf(sc[f][j] - mx[j]);
        ls[j] += p;
        Pw[(lg * 4 + j) * VST + f * 16 + lr] = (bf16)p;
      }
    }
    #pragma unroll
    for (int j = 0; j < 4; ++j) {
      #pragma unroll
      for (int off = 1; off < 16; off <<= 1) ls[j] += __shfl_xor(ls[j], off);
      ls[j] = 1.f / ls[j];
    }

    f32x4 oacc[4];
    #pragma unroll
    for (int n = 0; n < 4; ++n) oacc[n] = (f32x4){0.f, 0.f, 0.f, 0.f};
    #pragma unroll
    for (int kb = 0; kb < 7; ++kb) {
      const bf16x8 pa = *(const bf16x8*)&Pw[lr * VST + kb * 32 + lg * 8];
      #pragma unroll
      for (int n = 0; n < 4; ++n) {
        const bf16x8 bv = *(const bf16x8*)&Vt[(n * 16 + lr) * VST + kb * 32 + lg * 8];
        oacc[n] = __builtin_amdgcn_mfma_f32_16x16x32_bf16(pa, bv, oacc[n], 0, 0, 0);
      }
    }
    #pragma unroll
    for (int j = 0; j < 4; ++j) {
      const int row = q0 + lg * 4 + j;
      if (row < SS) {
        bf16* op = out + ((size_t)bp * SS + row) * 768 + h * HD;
        #pragma unroll
        for (int n = 0; n < 4; ++n) op[n * 16 + lr] = (bf16)(oacc[n][j] * ls[j]);
      }
    }
  }
}

// ---------------- temporal attention: wave per (b, s, h), T=8 ---------------
__global__ __launch_bounds__(256)
void attn_temporal(const bf16* __restrict__ qkv, bf16* __restrict__ out) {
  const int pair = blockIdx.x * 4 + (threadIdx.x >> 6);
  const int lane = threadIdx.x & 63;
  const int h = pair % 12;
  const int bs = pair / 12;
  const int b = bs / SS, s = bs - b * SS;
  const size_t row0 = (size_t)b * NTOK + s;
  const int q = lane >> 3, k = lane & 7;
  const bf16* qr = qkv + (row0 + (size_t)q * SS) * 2304 + h * HD;
  const bf16* kr = qkv + (row0 + (size_t)k * SS) * 2304 + 768 + h * HD;
  float sc = 0.f;
  #pragma unroll
  for (int j = 0; j < 8; ++j) {
    bf16x8 qv = ((const bf16x8*)qr)[j];
    bf16x8 kv = ((const bf16x8*)kr)[j];
    #pragma unroll
    for (int d = 0; d < 8; ++d) sc += (float)qv[d] * (float)kv[d];
  }
  sc *= 0.125f;
  float mxv = sc;
  #pragma unroll
  for (int off = 1; off < 8; off <<= 1) mxv = fmaxf(mxv, __shfl_xor(mxv, off));
  float p = __expf(sc - mxv);
  float sum = p;
  #pragma unroll
  for (int off = 1; off < 8; off <<= 1) sum += __shfl_xor(sum, off);
  p /= sum;

  const int dg = lane & 7;
  float o[8] = {0, 0, 0, 0, 0, 0, 0, 0};
  #pragma unroll
  for (int kk = 0; kk < 8; ++kk) {
    const float pk = __shfl(p, (lane & 56) + kk);
    const bf16* vr = qkv + (row0 + (size_t)kk * SS) * 2304 + 1536 + h * HD + dg * 8;
    bf16x8 vv = *(const bf16x8*)vr;
    #pragma unroll
    for (int j = 0; j < 8; ++j) o[j] += pk * (float)vv[j];
  }
  bf16* op = out + (row0 + (size_t)q * SS) * 768 + h * HD + dg * 8;
  bf16x8 ov;
  #pragma unroll
  for (int j = 0; j < 8; ++j) ov[j] = (bf16)o[j];
  *(bf16x8*)op = ov;
}

// ---------------- MoE: bucket n-indices by expert + 32-token descriptors ----
__global__ __launch_bounds__(256)
void sort_moe(const int* __restrict__ eids, int* __restrict__ perm,
              int4* __restrict__ descs, int* __restrict__ meta) {
  __shared__ int cnt[4], base[4], cur[4];
  const int tid = threadIdx.x;
  if (tid < 4) cnt[tid] = 0;
  __syncthreads();
  for (int n = tid; n < NTOK; n += 256) atomicAdd(&cnt[eids[n]], 1);
  __syncthreads();
  if (tid == 0) {
    int off = 0;
    for (int e = 0; e < 4; ++e) { base[e] = off; cur[e] = off; off += cnt[e]; }
  }
  __syncthreads();
  for (int n = tid; n < NTOK; n += 256) {
    const int pos = atomicAdd(&cur[eids[n]], 1);
    perm[pos] = n;
  }
  if (tid == 0) {
    int t = 0;
    for (int e = 0; e < 4; ++e)
      for (int st = 0; st < cnt[e]; st += 32) {
        const int c = cnt[e] - st;
        descs[t++] = make_int4(e, base[e] + st, c < 32 ? c : 32, 0);
      }
    meta[0] = t;
  }
}

// ---------------- launch ------------------------------------------------------
extern "C" void kernel_launch(void* const* d_in, const int* in_sizes, int n_in,
                              void* d_out, int out_size, void* d_ws, size_t ws_size,
                              hipStream_t stream) {
  (void)in_sizes; (void)n_in; (void)out_size; (void)ws_size;
  const float* x        = (const float*)d_in[0];
  const float* qkv_w_s  = (const float*)d_in[1];
  const float* qkv_b_s  = (const float*)d_in[2];
  const float* proj_w_s = (const float*)d_in[3];
  const float* proj_b_s = (const float*)d_in[4];
  const float* qkv_w_t  = (const float*)d_in[5];
  const float* qkv_b_t  = (const float*)d_in[6];
  const float* proj_w_t = (const float*)d_in[7];
  const float* proj_b_t = (const float*)d_in[8];
  const float* ln_s_g   = (const float*)d_in[9];
  const float* ln_s_b   = (const float*)d_in[10];
  const float* ln_t_g   = (const float*)d_in[11];
  const float* ln_t_b   = (const float*)d_in[12];
  const float* ln_m_g   = (const float*)d_in[13];
  const float* ln_m_b   = (const float*)d_in[14];
  const float* gate_up  = (const float*)d_in[15];
  const float* down_w   = (const float*)d_in[16];
  const int* expert_ids = (const int*)d_in[19];
  float* out = (float*)d_out;

  char* ws = (char*)d_ws;
  bf16* qkvsT   = (bf16*)(ws + 0);
  bf16* projsT  = (bf16*)(ws + 3538944);
  bf16* qkvtT   = (bf16*)(ws + 4718592);
  bf16* projtT  = (bf16*)(ws + 8257536);
  bf16* guT     = (bf16*)(ws + 9437184);
  bf16* downT   = (bf16*)(ws + 18874368);
  bf16* lnbuf   = (bf16*)(ws + 23592960);
  bf16* qkvbuf  = (bf16*)(ws + 42860544);   // qkv / inter buffer
  bf16* attnbuf = (bf16*)(ws + 100663296);
  float* x1     = (float*)(ws + 119930880);
  int*  perm    = (int*)(ws + 158466048);
  int4* descs   = (int4*)(ws + 158472320);
  int*  meta    = (int*)(ws + 158473952);

  const dim3 blk(256);
  const dim3 blk512(512);

  transpose_w<<<dim3(12, 36, 1), blk, 0, stream>>>(qkv_w_s, qkvsT, 768, 2304);
  transpose_w<<<dim3(12, 12, 1), blk, 0, stream>>>(proj_w_s, projsT, 768, 768);
  transpose_w<<<dim3(12, 36, 1), blk, 0, stream>>>(qkv_w_t, qkvtT, 768, 2304);
  transpose_w<<<dim3(12, 12, 1), blk, 0, stream>>>(proj_w_t, projtT, 768, 768);
  transpose_gu<<<dim3(12, 24, 4), blk, 0, stream>>>(gate_up, guT);
  transpose_w<<<dim3(12, 12, 4), blk, 0, stream>>>(down_w, downT, 768, 768);

  // stage 1: spatial
  ln_kernel<<<3136, blk, 0, stream>>>(x, ln_s_g, ln_s_b, lnbuf);
  gemmDP<false, true, false, true, false><<<dim3(49 * 9), blk512, 0, stream>>>(
      lnbuf, qkvsT, qkv_b_s, nullptr, nullptr, qkvbuf, 2304, 768, 49,
      nullptr, nullptr, nullptr);
  attn_spatial<<<dim3(64, 12), blk512, 0, stream>>>(qkvbuf, attnbuf);
  gemmDP<false, true, true, false, false><<<dim3(49 * 3), blk512, 0, stream>>>(
      attnbuf, projsT, proj_b_s, x, x1, nullptr, 768, 768, 49,
      nullptr, nullptr, nullptr);

  // stage 2: temporal
  ln_kernel<<<3136, blk, 0, stream>>>(x1, ln_t_g, ln_t_b, lnbuf);
  gemmDP<false, true, false, true, false><<<dim3(49 * 9), blk512, 0, stream>>>(
      lnbuf, qkvtT, qkv_b_t, nullptr, nullptr, qkvbuf, 2304, 768, 49,
      nullptr, nullptr, nullptr);
  attn_temporal<<<4704, blk, 0, stream>>>(qkvbuf, attnbuf);
  gemmDP<false, true, true, false, false><<<dim3(49 * 3), blk512, 0, stream>>>(
      attnbuf, projtT, proj_b_t, x1, out, nullptr, 768, 768, 49,
      nullptr, nullptr, nullptr);

  // stage 3: MoE MLP (silu fused into gate_up epilogue; inter in qkvbuf)
  ln_kernel<<<3136, blk, 0, stream>>>(out, ln_m_g, ln_m_b, lnbuf);
  sort_moe<<<1, blk, 0, stream>>>(expert_ids, perm, descs, meta);
  gemmDP<true, false, false, true, true><<<dim3(56, 6), blk512, 0, stream>>>(
      lnbuf, guT, nullptr, nullptr, nullptr, qkvbuf, 1536, 768, 0,
      perm, descs, meta);
  gemmDP<true, false, true, false, false><<<dim3(56, 3), blk512, 0, stream>>>(
      qkvbuf, downT, nullptr, out, out, nullptr, 768, 768, 0,
      perm, descs, meta);
}